// Round 10
// baseline (2259.092 us; speedup 1.0000x reference)
//
#include <hip/hip_runtime.h>
#include <stdint.h>

// Resonator network, b=1024 f=4 v=64 d=2048, 100 iterations.
// All values +-1 -> exact bit arithmetic. Round 10: FOUR rows per block,
// 256 blocks = 1/CU single round, __launch_bounds__(256,1) -> 256-VGPR cap
// (r9 proved the 128-cap serializes multi-row ILP). Table words loaded once
// per 4 rows. Row loops fully unrolled (compile-time indices); chunk loops
// rolled to bound code size. r8-validated machinery otherwise.

#define NB 1024
#define NF 4
#define ND 2048
#define NW 32            // ND/64 words per row
#define ITERS 100
#define NR 4             // rows per block

#define OFF_OUT  (NB*NF*ND)
#define OFF_MS   (OFF_OUT + NB*NF)
#define OFF_CONV (OFF_MS + NB*NF)

typedef unsigned long long u64;

// Pack codebooks (f,v,d) +-1 floats into two bit layouts in d_ws:
//  cbB[(j*32+w)*64 + v] : row bits, bit l = sign of cb[j,v,w*64+l]
//  cbT[j*2048 + d]      : column mask, bit v = sign of cb[j,v,d]
__global__ void pack_cb_kernel(const float* __restrict__ cb,
                               u64* __restrict__ cbB, u64* __restrict__ cbT) {
    const int lane = threadIdx.x & 63;
    const int gw   = (blockIdx.x * (blockDim.x >> 6)) + (threadIdx.x >> 6);
    const int nw   = (gridDim.x * blockDim.x) >> 6;
    for (int idx = gw; idx < NF * 64 * NW; idx += nw) {
        const int j = idx >> 11, v = (idx >> 5) & 63, w = idx & 31;
        const float x = cb[(((j << 6) | v) << 11) + (w << 6) + lane];
        const u64 m = __ballot(x < 0.0f);
        if (lane == 0) cbB[(((j << 5) | w) << 6) | v] = m;
    }
    for (int idx = gw; idx < NF * ND; idx += nw) {
        const int j = idx >> 11, d = idx & 2047;
        const float x = cb[(((j << 6) | lane) << 11) + d];
        const u64 m = __ballot(x < 0.0f);
        if (lane == 0) cbT[idx] = m;
    }
}

__global__ __launch_bounds__(256, 1) void resonator_kernel(
    const float* __restrict__ inp, const float* __restrict__ est_init,
    const u64* __restrict__ cbB, const u64* __restrict__ cbT,
    float* __restrict__ out) {
    __shared__ u64 s_hist[NR][4][NF][NW];   // [row][ring4][factor][word] 16 KB
    __shared__ u64 s_inp[NR][NW];
    __shared__ u64 s_ne[NR][NF][NW];        // own-wave use only
    __shared__ int s_conv[NR][NF];

    const int b     = blockIdx.x;           // 0..255
    const int tid   = threadIdx.x;
    const int j     = tid >> 6;             // wave = factor
    const int lane  = tid & 63;
    const int rBase = b << 2;               // rows rBase..rBase+3

    const u64* cbBj = cbB + (j << 11);
    const u64* cbTj = cbT + (j << 11);

    // ---- pack input + est_0 for all rows ----
    #pragma unroll
    for (int r = 0; r < NR; ++r) {
        #pragma unroll
        for (int k = 0; k < 8; ++k) {
            const int w = (j << 3) + k;
            const u64 m = __ballot(inp[((rBase + r) << 11) + (w << 6) + lane] < 0.0f);
            if (lane == 0) s_inp[r][w] = m;
        }
        #pragma unroll 4
        for (int w = 0; w < NW; ++w) {
            const u64 m = __ballot(
                est_init[((((rBase + r) << 2) | j) << 11) + (w << 6) + lane] < 0.0f);
            if (lane == 0) s_hist[r][0][j][w] = m;
        }
    }
    __syncthreads();

    int ml[NR] = {0, 0, 0, 0}, mp[NR] = {0, 0, 0, 0};
    int fs[NR] = {0, 0, 0, 0};

    for (int it = 0; it < ITERS; ++it) {
        const int cur = it & 3, nxt = (it + 1) & 3, prv = (it + 3) & 3;

        // ne for own factor, all rows (own-wave LDS -> no barrier needed)
        if (lane < NW) {
            #pragma unroll
            for (int r = 0; r < NR; ++r) {
                const u64 X = s_inp[r][lane]
                    ^ s_hist[r][cur][0][lane] ^ s_hist[r][cur][1][lane]
                    ^ s_hist[r][cur][2][lane] ^ s_hist[r][cur][3][lane];
                s_ne[r][j][lane] = X ^ s_hist[r][cur][j][lane];
            }
        }

        // ---- phase B: pc_v all rows; each cbB word loaded once ----
        int pc[NR] = {0, 0, 0, 0};
        #pragma unroll 2
        for (int ch = 0; ch < 8; ++ch) {
            const int w4 = ch << 2;
            u64 g[4];
            #pragma unroll
            for (int k = 0; k < 4; ++k) g[k] = cbBj[((w4 + k) << 6) | lane];
            #pragma unroll
            for (int r = 0; r < NR; ++r) {
                #pragma unroll
                for (int k = 0; k < 4; ++k)
                    pc[r] += (int)__popcll(s_ne[r][j][w4 + k] ^ g[k]);
            }
        }

        int mn[NR], sp[NR];
        #pragma unroll
        for (int r = 0; r < NR; ++r) { mn[r] = pc[r]; sp[r] = pc[r]; }
        #pragma unroll
        for (int off = 32; off > 0; off >>= 1) {
            #pragma unroll
            for (int r = 0; r < NR; ++r) {
                const int a1 = __shfl_xor(mn[r], off);
                const int a2 = __shfl_xor(sp[r], off);
                mn[r] = mn[r] < a1 ? mn[r] : a1;
                sp[r] += a2;
            }
        }
        #pragma unroll
        for (int r = 0; r < NR; ++r) { mp[r] = ml[r]; ml[r] = ND - 2 * mn[r]; }

        // ---- mean-centered exact decomposition, per row ----
        u64 c[NR][8];
        int base[NR], cmul[NR], oe0[NR], oe1[NR], ov0[NR], ov1[NR], nov[NR];
        u64 om[NR];
        int ex[NR];
        #pragma unroll
        for (int r = 0; r < NR; ++r) {
            const int mean = sp[r] >> 6;
            const int dev  = pc[r] - mean;
            const int devc = dev < -128 ? -128 : (dev > 127 ? 127 : dev);
            ex[r] = dev - devc;
            const int u = devc + 128;       // 0..255
            c[r][0] = __ballot(u & 1);   c[r][1] = __ballot(u & 2);
            c[r][2] = __ballot(u & 4);   c[r][3] = __ballot(u & 8);
            c[r][4] = __ballot(u & 16);  c[r][5] = __ballot(u & 32);
            c[r][6] = __ballot(u & 64);  c[r][7] = __ballot(u & 128);
            u64 o = __ballot(ex[r] != 0);
            nov[r] = (int)__popcll(o);
            ov0[r] = 0; ov1[r] = 0; oe0[r] = 0; oe1[r] = 0;
            if (nov[r] > 0) {
                ov0[r] = __builtin_ctzll(o); o &= o - 1;
                oe0[r] = 4 * __builtin_amdgcn_readlane(ex[r], ov0[r]);
                if (nov[r] > 1) {
                    ov1[r] = __builtin_ctzll(o); o &= o - 1;
                    oe1[r] = 4 * __builtin_amdgcn_readlane(ex[r], ov1[r]);
                }
            }
            om[r]   = o;                    // outliers beyond first two
            base[r] = 131072 - 2 * sp[r];
            cmul[r] = 4 * mean - 4608;
        }

        // ---- phase C: each cbT word loaded once, 4 rows computed ----
        #pragma unroll 2
        for (int ch = 0; ch < 8; ++ch) {
            const int w4 = ch << 2;
            u64 cw[4];
            #pragma unroll
            for (int k = 0; k < 4; ++k) cw[k] = cbTj[((w4 + k) << 6) | lane];
            #pragma unroll
            for (int k2 = 0; k2 < 4; ++k2) {
                const u64 g = cw[k2];
                const int colb = (int)__popcll(g);
                #pragma unroll
                for (int r = 0; r < NR; ++r) {
                    int t = base[r] + cmul[r] * colb;
                    t += (int)__popcll(c[r][0] & g) << 2;
                    t += (int)__popcll(c[r][1] & g) << 3;
                    t += (int)__popcll(c[r][2] & g) << 4;
                    t += (int)__popcll(c[r][3] & g) << 5;
                    t += (int)__popcll(c[r][4] & g) << 6;
                    t += (int)__popcll(c[r][5] & g) << 7;
                    t += (int)__popcll(c[r][6] & g) << 8;
                    t += (int)__popcll(c[r][7] & g) << 9;
                    t += oe0[r] * (int)((g >> ov0[r]) & 1);
                    t += oe1[r] * (int)((g >> ov1[r]) & 1);
                    if (nov[r] > 2) {                // exact, ~never taken
                        u64 m2 = om[r];
                        while (m2) {
                            const int vv = __builtin_ctzll(m2); m2 &= m2 - 1;
                            t += 4 * __builtin_amdgcn_readlane(ex[r], vv)
                                   * (int)((g >> vv) & 1);
                        }
                    }
                    const u64 nww = __ballot(t < 0);
                    if (lane == 0) s_hist[r][nxt][j][w4 + k2] = nww;
                }
            }
        }

        // ---- period<=2 check, all rows ----
        #pragma unroll
        for (int r = 0; r < NR; ++r) {
            int d1 = 0, d2 = 0;
            if (lane < NW) {
                const u64 a = s_hist[r][nxt][j][lane];
                d1 = (a != s_hist[r][cur][j][lane]);
                d2 = (a != s_hist[r][prv][j][lane]);
            }
            const u64 b1 = __ballot(d1), b2 = __ballot(d2);
            if (lane == 0)
                s_conv[r][j] = (b1 == 0 ? 1 : 0) | (b2 == 0 ? 2 : 0);
        }
        __syncthreads();                          // the one barrier per iter

        int fl[NR];
        bool allok = true;
        #pragma unroll
        for (int r = 0; r < NR; ++r) {
            fl[r] = s_conv[r][0] & s_conv[r][1] & s_conv[r][2] & s_conv[r][3];
            fs[r] = nxt;
            const bool ok = (fl[r] & 1) || (it >= 1 && (fl[r] & 2));
            allok = allok && ok;
        }
        if (allok) {
            #pragma unroll
            for (int r = 0; r < NR; ++r) {
                if (!(fl[r] & 1) && ((ITERS - it) & 1) == 0) {
                    fs[r] = cur; ml[r] = mp[r];
                }
            }
            break;
        }
    }

    // ---- epilogue per row: outcome + max_sim + unpack ----
    #pragma unroll
    for (int r = 0; r < NR; ++r) {
        int pcO = 0;
        #pragma unroll
        for (int w = 0; w < NW; ++w)
            pcO += (int)__popcll(s_hist[r][fs[r]][j][w] ^ cbBj[(w << 6) | lane]);
        const int simF = ND - (pcO << 1);
        const int aF   = simF < 0 ? -simF : simF;
        int key = (aF << 6) | (63 - lane);
        #pragma unroll
        for (int off = 32; off > 0; off >>= 1) {
            const int t1 = __shfl_xor(key, off);
            key = key > t1 ? key : t1;
        }
        if (lane == 0) {
            out[OFF_OUT + ((rBase + r) << 2) + j] = (float)(63 - (key & 63));
            out[OFF_MS  + ((rBase + r) << 2) + j] = (float)ml[r];
        }
        #pragma unroll 4
        for (int k = 0; k < 32; ++k) {
            const int idx = tid + (k << 8);        // 0..8191
            const int jj = idx >> 11, d = idx & 2047;
            const u64 wrd = s_hist[r][fs[r]][jj][d >> 6];
            out[((rBase + r) << 13) + idx] = ((wrd >> (d & 63)) & 1) ? -1.0f : 1.0f;
        }
    }
    if (b == 0 && tid == 0) out[OFF_CONV] = 99.0f;
}

extern "C" void kernel_launch(void* const* d_in, const int* in_sizes, int n_in,
                              void* d_out, int out_size, void* d_ws, size_t ws_size,
                              hipStream_t stream) {
    const float* inp  = (const float*)d_in[0];
    const float* est0 = (const float*)d_in[1];
    const float* cb   = (const float*)d_in[2];
    float* out = (float*)d_out;
    u64* cbB = (u64*)d_ws;                 // 8192 words
    u64* cbT = cbB + NF * 64 * NW;         // 8192 words (128 KB of ws total)

    pack_cb_kernel<<<64, 256, 0, stream>>>(cb, cbB, cbT);
    resonator_kernel<<<NB / NR, 256, 0, stream>>>(inp, est0, cbB, cbT, out);
}

// Round 11
// 1673.062 us; speedup vs baseline: 1.3503x; 1.3503x over previous
//
#include <hip/hip_runtime.h>
#include <stdint.h>

// Resonator network, b=1024 f=4 v=64 d=2048, 100 iterations.
// All values +-1 -> exact bit arithmetic. Round 11: BOTH bit-tables in LDS
// (128 KB, relaid [j][w2][lane][2] so every table access is ds_read_b128
// off one shared vaddr + immediate offset -> zero address math, no L2
// latency), 16 waves/block (wave = factor x row, 4 rows/block, 256 blocks
// = 1/CU single round, 4 waves/SIMD). Per-wave work = r8's proven 1-row
// shape (mean-centered 8 planes + 2 exact outliers + exact >2 fallback,
// free msim, period<=2 joint exit, 1 barrier/iter). Ring cut to 3 slots.

#define NB 1024
#define NF 4
#define ND 2048
#define NW 32            // ND/64 words per row
#define ITERS 100
#define NRB 4            // rows per block

#define OFF_OUT  (NB*NF*ND)
#define OFF_MS   (OFF_OUT + NB*NF)
#define OFF_CONV (OFF_MS + NB*NF)

typedef unsigned long long u64;

// Pack codebooks into the LDS-friendly layout, directly in d_ws:
//  cbB[((j*16+w2)*64 + v)*2 + k] : row-bits word for (j, w=2*w2+k, v)
//  cbT[((j*16+w2)*64 + la)*2 + k]: column mask for (j, d=(2*w2+k)*64+la)
__global__ void pack_cb_kernel(const float* __restrict__ cb,
                               u64* __restrict__ cbB, u64* __restrict__ cbT) {
    const int lane = threadIdx.x & 63;
    const int gw   = (blockIdx.x * (blockDim.x >> 6)) + (threadIdx.x >> 6);
    const int nw   = (gridDim.x * blockDim.x) >> 6;
    for (int idx = gw; idx < NF * 64 * NW; idx += nw) {
        const int j = idx >> 11, v = (idx >> 5) & 63, w = idx & 31;
        const float x = cb[(((j << 6) | v) << 11) + (w << 6) + lane];
        const u64 m = __ballot(x < 0.0f);
        if (lane == 0)
            cbB[(((((j << 4) | (w >> 1)) << 6) | v) << 1) | (w & 1)] = m;
    }
    for (int idx = gw; idx < NF * ND; idx += nw) {
        const int j = idx >> 11, d = idx & 2047;
        const float x = cb[(((j << 6) | lane) << 11) + d];
        const u64 m = __ballot(x < 0.0f);
        const int w = d >> 6, la = d & 63;
        if (lane == 0)
            cbT[(((((j << 4) | (w >> 1)) << 6) | la) << 1) | (w & 1)] = m;
    }
}

// per-word phase-C body
#define PCW(CW, W)                                                           \
    {                                                                        \
        const u64 cw_ = (CW);                                                \
        int t = base + cmul * (int)__popcll(cw_);                            \
        t += (int)__popcll(c0 & cw_) << 2;                                   \
        t += (int)__popcll(c1 & cw_) << 3;                                   \
        t += (int)__popcll(c2 & cw_) << 4;                                   \
        t += (int)__popcll(c3 & cw_) << 5;                                   \
        t += (int)__popcll(c4 & cw_) << 6;                                   \
        t += (int)__popcll(c5 & cw_) << 7;                                   \
        t += (int)__popcll(c6 & cw_) << 8;                                   \
        t += (int)__popcll(c7 & cw_) << 9;                                   \
        t += oe0 * (int)((cw_ >> ov0) & 1);                                  \
        t += oe1 * (int)((cw_ >> ov1) & 1);                                  \
        if (nov > 2) {                           /* exact, ~never taken */   \
            u64 m2 = om;                                                     \
            while (m2) {                                                     \
                const int vv = __builtin_ctzll(m2); m2 &= m2 - 1;            \
                t += 4 * __builtin_amdgcn_readlane(ex, vv)                   \
                       * (int)((cw_ >> vv) & 1);                             \
            }                                                                \
        }                                                                    \
        const u64 nww = __ballot(t < 0);                                     \
        if (lane == 0) s_hist[r][nxt][j][W] = nww;                           \
    }

__global__ __launch_bounds__(1024, 4) void resonator_kernel(
    const float* __restrict__ inp, const float* __restrict__ est_init,
    const u64* __restrict__ cbB, const u64* __restrict__ cbT,
    float* __restrict__ out) {
    __shared__ u64 l_cbB[NF * 16 * 64 * 2];   // 64 KB, [j][w2][lane][k]
    __shared__ u64 l_cbT[NF * 16 * 64 * 2];   // 64 KB
    __shared__ u64 s_hist[NRB][3][NF][NW];    // 12 KB, 3-slot ring
    __shared__ u64 s_inp[NRB][NW];            // 1 KB
    __shared__ u64 s_ne[NRB][NF][NW];         // 4 KB
    __shared__ int s_conv[NRB][NF];
    __shared__ int s_fs[NRB];

    const int b    = blockIdx.x;          // 0..255
    const int tid  = threadIdx.x;
    const int wid  = tid >> 6;            // 0..15
    const int lane = tid & 63;
    const int j    = wid & 3;             // factor
    const int r    = wid >> 2;            // row-in-block
    const int row  = (b << 2) + r;

    // ---- copy tables to LDS (one-time) ----
    for (int idx = tid; idx < NF * 16 * 64 * 2; idx += 1024) {
        l_cbB[idx] = cbB[idx];
        l_cbT[idx] = cbT[idx];
    }
    // ---- pack input + est_0 ----
    #pragma unroll
    for (int k = 0; k < 8; ++k) {
        const int w = (j << 3) + k;
        const u64 m = __ballot(inp[(row << 11) + (w << 6) + lane] < 0.0f);
        if (lane == 0) s_inp[r][w] = m;
    }
    #pragma unroll 4
    for (int w = 0; w < NW; ++w) {
        const u64 m = __ballot(
            est_init[(((row << 2) | j) << 11) + (w << 6) + lane] < 0.0f);
        if (lane == 0) s_hist[r][0][j][w] = m;
    }
    __syncthreads();

    const ulonglong2* tB = (const ulonglong2*)l_cbB + (j << 10) + lane;
    const ulonglong2* tT = (const ulonglong2*)l_cbT + (j << 10) + lane;

    int ml = 0, mp = 0, fs = 0;
    int cur = 0, nxt = 1, prv = 2;

    for (int it = 0; it < ITERS; ++it) {
        // ne for own (row, factor); own-wave LDS -> no barrier needed
        if (lane < NW) {
            const u64 X = s_inp[r][lane]
                ^ s_hist[r][cur][0][lane] ^ s_hist[r][cur][1][lane]
                ^ s_hist[r][cur][2][lane] ^ s_hist[r][cur][3][lane];
            s_ne[r][j][lane] = X ^ s_hist[r][cur][j][lane];
        }

        // ---- phase B: pc_v; lane = v; b128 pair loads, imm offsets ----
        int pc = 0;
        #pragma unroll
        for (int w2 = 0; w2 < 16; ++w2) {
            const ulonglong2 g  = tB[w2 << 6];
            const ulonglong2 nn = *(const ulonglong2*)&s_ne[r][j][w2 << 1];
            pc += (int)__popcll(nn.x ^ g.x) + (int)__popcll(nn.y ^ g.y);
        }
        int mn = pc, sp = pc;
        #pragma unroll
        for (int off = 32; off > 0; off >>= 1) {
            const int a1 = __shfl_xor(mn, off);
            const int a2 = __shfl_xor(sp, off);
            mn = mn < a1 ? mn : a1;
            sp += a2;
        }
        mp = ml; ml = ND - 2 * mn;       // max_sim of this step, free

        // ---- mean-centered exact decomposition (r8) ----
        const int mean = sp >> 6;
        const int dev  = pc - mean;
        const int devc = dev < -128 ? -128 : (dev > 127 ? 127 : dev);
        const int ex   = dev - devc;
        const int u    = devc + 128;      // 0..255
        const u64 c0 = __ballot(u & 1),  c1 = __ballot(u & 2);
        const u64 c2 = __ballot(u & 4),  c3 = __ballot(u & 8);
        const u64 c4 = __ballot(u & 16), c5 = __ballot(u & 32);
        const u64 c6 = __ballot(u & 64), c7 = __ballot(u & 128);
        u64 om = __ballot(ex != 0);
        const int nov = (int)__popcll(om);
        int ov0 = 0, ov1 = 0, oe0 = 0, oe1 = 0;
        if (nov > 0) {
            ov0 = __builtin_ctzll(om); om &= om - 1;
            oe0 = 4 * __builtin_amdgcn_readlane(ex, ov0);
            if (nov > 1) {
                ov1 = __builtin_ctzll(om); om &= om - 1;
                oe1 = 4 * __builtin_amdgcn_readlane(ex, ov1);
            }
        }
        const int base = 131072 - 2 * sp;
        const int cmul = 4 * mean - 4608;

        // ---- phase C: lane = d%64; b128 pair loads, imm offsets ----
        #pragma unroll
        for (int w2 = 0; w2 < 16; ++w2) {
            const ulonglong2 g = tT[w2 << 6];
            PCW(g.x, (w2 << 1))
            PCW(g.y, (w2 << 1) + 1)
        }

        // ---- period<=2 check ----
        int d1 = 0, d2 = 0;
        if (lane < NW) {
            const u64 a = s_hist[r][nxt][j][lane];
            d1 = (a != s_hist[r][cur][j][lane]);
            d2 = (a != s_hist[r][prv][j][lane]);  // it=0 garbage, guarded
        }
        const u64 b1 = __ballot(d1), b2 = __ballot(d2);
        if (lane == 0) s_conv[r][j] = (b1 == 0 ? 1 : 0) | (b2 == 0 ? 2 : 0);
        __syncthreads();                          // the one barrier per iter

        int flr = 0;
        bool allok = true;
        #pragma unroll
        for (int r2 = 0; r2 < NRB; ++r2) {
            const int f = s_conv[r2][0] & s_conv[r2][1]
                        & s_conv[r2][2] & s_conv[r2][3];
            if (r2 == r) flr = f;
            allok = allok && ((f & 1) || (it >= 1 && (f & 2)));
        }
        fs = nxt;
        if (allok) {
            if (!(flr & 1) && ((ITERS - it) & 1) == 0) { fs = cur; ml = mp; }
            break;
        }
        const int t3 = prv; prv = cur; cur = nxt; nxt = t3;
    }

    if (j == 0 && lane == 0) s_fs[r] = fs;

    // ---- outcome: argmax_v |sim(est_100, cb)| (own row, own factor) ----
    int pcO = 0;
    #pragma unroll
    for (int w2 = 0; w2 < 16; ++w2) {
        const ulonglong2 g  = tB[w2 << 6];
        const ulonglong2 hh = *(const ulonglong2*)&s_hist[r][fs][j][w2 << 1];
        pcO += (int)__popcll(hh.x ^ g.x) + (int)__popcll(hh.y ^ g.y);
    }
    const int simF = ND - (pcO << 1);
    const int aF   = simF < 0 ? -simF : simF;
    int key = (aF << 6) | (63 - lane);
    #pragma unroll
    for (int off = 32; off > 0; off >>= 1) {
        const int t1 = __shfl_xor(key, off);
        key = key > t1 ? key : t1;
    }
    if (lane == 0) {
        out[OFF_OUT + (row << 2) + j] = (float)(63 - (key & 63));
        out[OFF_MS  + (row << 2) + j] = (float)ml;
    }
    __syncthreads();                     // s_fs + last ring writes visible

    // ---- unpack est_100, all 4 rows, 1024 threads ----
    #pragma unroll
    for (int rr = 0; rr < NRB; ++rr) {
        const int f2 = s_fs[rr];
        #pragma unroll
        for (int k = 0; k < 8; ++k) {
            const int idx = tid + (k << 10);      // 0..8191
            const int jj = idx >> 11, d = idx & 2047;
            const u64 wrd = s_hist[rr][f2][jj][d >> 6];
            out[(((b << 2) + rr) << 13) + idx] =
                ((wrd >> (d & 63)) & 1) ? -1.0f : 1.0f;
        }
    }
    if (b == 0 && tid == 0) out[OFF_CONV] = 99.0f;
}

extern "C" void kernel_launch(void* const* d_in, const int* in_sizes, int n_in,
                              void* d_out, int out_size, void* d_ws, size_t ws_size,
                              hipStream_t stream) {
    const float* inp  = (const float*)d_in[0];
    const float* est0 = (const float*)d_in[1];
    const float* cb   = (const float*)d_in[2];
    float* out = (float*)d_out;
    u64* cbB = (u64*)d_ws;                 // 8192 words
    u64* cbT = cbB + NF * 16 * 64 * 2;     // 8192 words (128 KB of ws total)

    pack_cb_kernel<<<64, 256, 0, stream>>>(cb, cbB, cbT);
    resonator_kernel<<<NB / NRB, 1024, 0, stream>>>(inp, est0, cbB, cbT, out);
}

// Round 12
// 1631.504 us; speedup vs baseline: 1.3847x; 1.0255x over previous
//
#include <hip/hip_runtime.h>
#include <stdint.h>

// Resonator network, b=1024 f=4 v=64 d=2048, 100 iterations.
// All values +-1 -> exact bit arithmetic. Round 12: r11 structure (LDS
// tables, 16 waves = factor x row, 4 rows/block, 256 blocks, 1 barrier/iter)
// with the stalls attacked: (1) explicit 8-deep register hoist of all
// ds_read_b128 table reads (r11's VGPR=52 shows compiler exposed LDS latency
// per word); (2) min-reduce dropped from the loop -- max_sim recomputed in
// the epilogue from the slot-99 state (r5-proven mapping); (3)
// __launch_bounds__(1024,2): empirical VGPR cap ~ 256/arg, so arg=2 -> 128
// cap for the hoisted registers (arg=4 would cap at 64 and spill).

#define NB 1024
#define NF 4
#define ND 2048
#define NW 32            // ND/64 words per row
#define ITERS 100
#define NRB 4            // rows per block

#define OFF_OUT  (NB*NF*ND)
#define OFF_MS   (OFF_OUT + NB*NF)
#define OFF_CONV (OFF_MS + NB*NF)

typedef unsigned long long u64;

// Pack codebooks into the LDS-friendly layout, directly in d_ws:
//  cbB[((j*16+w2)*64 + v)*2 + k] : row-bits word for (j, w=2*w2+k, v)
//  cbT[((j*16+w2)*64 + la)*2 + k]: column mask for (j, d=(2*w2+k)*64+la)
__global__ void pack_cb_kernel(const float* __restrict__ cb,
                               u64* __restrict__ cbB, u64* __restrict__ cbT) {
    const int lane = threadIdx.x & 63;
    const int gw   = (blockIdx.x * (blockDim.x >> 6)) + (threadIdx.x >> 6);
    const int nw   = (gridDim.x * blockDim.x) >> 6;
    for (int idx = gw; idx < NF * 64 * NW; idx += nw) {
        const int j = idx >> 11, v = (idx >> 5) & 63, w = idx & 31;
        const float x = cb[(((j << 6) | v) << 11) + (w << 6) + lane];
        const u64 m = __ballot(x < 0.0f);
        if (lane == 0)
            cbB[(((((j << 4) | (w >> 1)) << 6) | v) << 1) | (w & 1)] = m;
    }
    for (int idx = gw; idx < NF * ND; idx += nw) {
        const int j = idx >> 11, d = idx & 2047;
        const float x = cb[(((j << 6) | lane) << 11) + d];
        const u64 m = __ballot(x < 0.0f);
        const int w = d >> 6, la = d & 63;
        if (lane == 0)
            cbT[(((((j << 4) | (w >> 1)) << 6) | la) << 1) | (w & 1)] = m;
    }
}

// per-word phase-C body
#define PCW(CW, W)                                                           \
    {                                                                        \
        const u64 cw_ = (CW);                                                \
        int t = base + cmul * (int)__popcll(cw_);                            \
        t += (int)__popcll(c0 & cw_) << 2;                                   \
        t += (int)__popcll(c1 & cw_) << 3;                                   \
        t += (int)__popcll(c2 & cw_) << 4;                                   \
        t += (int)__popcll(c3 & cw_) << 5;                                   \
        t += (int)__popcll(c4 & cw_) << 6;                                   \
        t += (int)__popcll(c5 & cw_) << 7;                                   \
        t += (int)__popcll(c6 & cw_) << 8;                                   \
        t += (int)__popcll(c7 & cw_) << 9;                                   \
        t += oe0 * (int)((cw_ >> ov0) & 1);                                  \
        t += oe1 * (int)((cw_ >> ov1) & 1);                                  \
        if (nov > 2) {                           /* exact, ~never taken */   \
            u64 m2 = om;                                                     \
            while (m2) {                                                     \
                const int vv = __builtin_ctzll(m2); m2 &= m2 - 1;            \
                t += 4 * __builtin_amdgcn_readlane(ex, vv)                   \
                       * (int)((cw_ >> vv) & 1);                             \
            }                                                                \
        }                                                                    \
        const u64 nww = __ballot(t < 0);                                     \
        if (lane == 0) s_hist[r][nxt][j][W] = nww;                           \
    }

__global__ __launch_bounds__(1024, 2) void resonator_kernel(
    const float* __restrict__ inp, const float* __restrict__ est_init,
    const u64* __restrict__ cbB, const u64* __restrict__ cbT,
    float* __restrict__ out) {
    __shared__ u64 l_cbB[NF * 16 * 64 * 2];   // 64 KB, [j][w2][lane][k]
    __shared__ u64 l_cbT[NF * 16 * 64 * 2];   // 64 KB
    __shared__ u64 s_hist[NRB][3][NF][NW];    // 12 KB, 3-slot ring
    __shared__ u64 s_inp[NRB][NW];            // 1 KB
    __shared__ u64 s_ne[NRB][NF][NW];         // 4 KB
    __shared__ int s_conv[NRB][NF];
    __shared__ int s_fs[NRB];

    const int b    = blockIdx.x;          // 0..255
    const int tid  = threadIdx.x;
    const int wid  = tid >> 6;            // 0..15
    const int lane = tid & 63;
    const int j    = wid & 3;             // factor
    const int r    = wid >> 2;            // row-in-block
    const int row  = (b << 2) + r;

    // ---- copy tables to LDS (one-time) ----
    for (int idx = tid; idx < NF * 16 * 64 * 2; idx += 1024) {
        l_cbB[idx] = cbB[idx];
        l_cbT[idx] = cbT[idx];
    }
    // ---- pack input + est_0 ----
    #pragma unroll
    for (int k = 0; k < 8; ++k) {
        const int w = (j << 3) + k;
        const u64 m = __ballot(inp[(row << 11) + (w << 6) + lane] < 0.0f);
        if (lane == 0) s_inp[r][w] = m;
    }
    #pragma unroll 4
    for (int w = 0; w < NW; ++w) {
        const u64 m = __ballot(
            est_init[(((row << 2) | j) << 11) + (w << 6) + lane] < 0.0f);
        if (lane == 0) s_hist[r][0][j][w] = m;
    }
    __syncthreads();

    const ulonglong2* tB = (const ulonglong2*)l_cbB + (j << 10) + lane;
    const ulonglong2* tT = (const ulonglong2*)l_cbT + (j << 10) + lane;

    int s100 = -1, s99 = -1;
    int cur = 0, nxt = 1, prv = 2;

    for (int it = 0; it < ITERS; ++it) {
        // ne for own (row, factor); own-wave LDS -> no barrier needed
        if (lane < NW) {
            const u64 X = s_inp[r][lane]
                ^ s_hist[r][cur][0][lane] ^ s_hist[r][cur][1][lane]
                ^ s_hist[r][cur][2][lane] ^ s_hist[r][cur][3][lane];
            s_ne[r][j][lane] = X ^ s_hist[r][cur][j][lane];
        }

        // ---- phase B: pc_v; lane = v; 8-deep hoisted b128 loads ----
        int pc = 0;
        #pragma unroll
        for (int hh = 0; hh < 2; ++hh) {
            ulonglong2 gB[8];
            #pragma unroll
            for (int k = 0; k < 8; ++k)
                gB[k] = tB[((hh << 3) | k) << 6];
            #pragma unroll
            for (int k = 0; k < 8; ++k) {
                const int w2 = (hh << 3) | k;
                const ulonglong2 nn =
                    *(const ulonglong2*)&s_ne[r][j][w2 << 1];
                pc += (int)__popcll(nn.x ^ gB[k].x)
                    + (int)__popcll(nn.y ^ gB[k].y);
            }
        }
        int sp = pc;
        #pragma unroll
        for (int off = 32; off > 0; off >>= 1) sp += __shfl_xor(sp, off);

        // ---- mean-centered exact decomposition ----
        const int mean = sp >> 6;
        const int dev  = pc - mean;
        const int devc = dev < -128 ? -128 : (dev > 127 ? 127 : dev);
        const int ex   = dev - devc;
        const int u    = devc + 128;      // 0..255
        const u64 c0 = __ballot(u & 1),  c1 = __ballot(u & 2);
        const u64 c2 = __ballot(u & 4),  c3 = __ballot(u & 8);
        const u64 c4 = __ballot(u & 16), c5 = __ballot(u & 32);
        const u64 c6 = __ballot(u & 64), c7 = __ballot(u & 128);
        u64 om = __ballot(ex != 0);
        const int nov = (int)__popcll(om);
        int ov0 = 0, ov1 = 0, oe0 = 0, oe1 = 0;
        if (nov > 0) {
            ov0 = __builtin_ctzll(om); om &= om - 1;
            oe0 = 4 * __builtin_amdgcn_readlane(ex, ov0);
            if (nov > 1) {
                ov1 = __builtin_ctzll(om); om &= om - 1;
                oe1 = 4 * __builtin_amdgcn_readlane(ex, ov1);
            }
        }
        const int base = 131072 - 2 * sp;
        const int cmul = 4 * mean - 4608;

        // ---- phase C: lane = d%64; 8-deep hoisted b128 loads ----
        #pragma unroll
        for (int hh = 0; hh < 2; ++hh) {
            ulonglong2 gT[8];
            #pragma unroll
            for (int k = 0; k < 8; ++k)
                gT[k] = tT[((hh << 3) | k) << 6];
            #pragma unroll
            for (int k = 0; k < 8; ++k) {
                const int w2 = (hh << 3) | k;
                PCW(gT[k].x, (w2 << 1))
                PCW(gT[k].y, (w2 << 1) + 1)
            }
        }

        // ---- period<=2 check ----
        int d1 = 0, d2 = 0;
        if (lane < NW) {
            const u64 a = s_hist[r][nxt][j][lane];
            d1 = (a != s_hist[r][cur][j][lane]);
            d2 = (a != s_hist[r][prv][j][lane]);  // it=0 garbage, guarded
        }
        const u64 b1 = __ballot(d1), b2 = __ballot(d2);
        if (lane == 0) s_conv[r][j] = (b1 == 0 ? 1 : 0) | (b2 == 0 ? 2 : 0);
        __syncthreads();                          // the one barrier per iter

        int flr = 0;
        bool allok = true;
        #pragma unroll
        for (int r2 = 0; r2 < NRB; ++r2) {
            const int f = s_conv[r2][0] & s_conv[r2][1]
                        & s_conv[r2][2] & s_conv[r2][3];
            if (r2 == r) flr = f;
            allok = allok && ((f & 1) || (it >= 1 && (f & 2)));
        }
        if (allok) {
            if (flr & 1) { s100 = nxt; s99 = nxt; }
            else {
                s100 = (((ITERS - it) & 1) == 0) ? cur : nxt;
                s99  = (s100 == nxt) ? cur : nxt;
            }
            break;
        }
        const int t3 = prv; prv = cur; cur = nxt; nxt = t3;
    }
    if (s100 < 0) { s100 = cur; s99 = prv; }   // natural end, post-rotation

    if (j == 0 && lane == 0) s_fs[r] = s100;

    // ---- outcome: argmax_v |sim(est_100, cb)| (own row, own factor) ----
    int pcO = 0;
    #pragma unroll
    for (int w2 = 0; w2 < 16; ++w2) {
        const ulonglong2 g  = tB[w2 << 6];
        const ulonglong2 hh = *(const ulonglong2*)&s_hist[r][s100][j][w2 << 1];
        pcO += (int)__popcll(hh.x ^ g.x) + (int)__popcll(hh.y ^ g.y);
    }
    const int simF = ND - (pcO << 1);
    const int aF   = simF < 0 ? -simF : simF;
    int key = (aF << 6) | (63 - lane);
    #pragma unroll
    for (int off = 32; off > 0; off >>= 1) {
        const int t1 = __shfl_xor(key, off);
        key = key > t1 ? key : t1;
    }

    // ---- max_sims[-1] = ND - 2*min_v pc on ne(est_99) (slot s99) ----
    int pc9 = 0;
    #pragma unroll
    for (int w2 = 0; w2 < 16; ++w2) {
        const ulonglong2 g = tB[w2 << 6];
        const int w = w2 << 1;
        const u64 X0 = s_inp[r][w]
            ^ s_hist[r][s99][0][w] ^ s_hist[r][s99][1][w]
            ^ s_hist[r][s99][2][w] ^ s_hist[r][s99][3][w];
        const u64 n0 = X0 ^ s_hist[r][s99][j][w];
        const u64 X1 = s_inp[r][w + 1]
            ^ s_hist[r][s99][0][w + 1] ^ s_hist[r][s99][1][w + 1]
            ^ s_hist[r][s99][2][w + 1] ^ s_hist[r][s99][3][w + 1];
        const u64 n1 = X1 ^ s_hist[r][s99][j][w + 1];
        pc9 += (int)__popcll(n0 ^ g.x) + (int)__popcll(n1 ^ g.y);
    }
    int mn9 = pc9;
    #pragma unroll
    for (int off = 32; off > 0; off >>= 1) {
        const int a1 = __shfl_xor(mn9, off);
        mn9 = mn9 < a1 ? mn9 : a1;
    }
    if (lane == 0) {
        out[OFF_OUT + (row << 2) + j] = (float)(63 - (key & 63));
        out[OFF_MS  + (row << 2) + j] = (float)(ND - 2 * mn9);
    }
    __syncthreads();                     // s_fs + last ring writes visible

    // ---- unpack est_100, all 4 rows, 1024 threads ----
    #pragma unroll
    for (int rr = 0; rr < NRB; ++rr) {
        const int f2 = s_fs[rr];
        #pragma unroll
        for (int k = 0; k < 8; ++k) {
            const int idx = tid + (k << 10);      // 0..8191
            const int jj = idx >> 11, d = idx & 2047;
            const u64 wrd = s_hist[rr][f2][jj][d >> 6];
            out[(((b << 2) + rr) << 13) + idx] =
                ((wrd >> (d & 63)) & 1) ? -1.0f : 1.0f;
        }
    }
    if (b == 0 && tid == 0) out[OFF_CONV] = 99.0f;
}

extern "C" void kernel_launch(void* const* d_in, const int* in_sizes, int n_in,
                              void* d_out, int out_size, void* d_ws, size_t ws_size,
                              hipStream_t stream) {
    const float* inp  = (const float*)d_in[0];
    const float* est0 = (const float*)d_in[1];
    const float* cb   = (const float*)d_in[2];
    float* out = (float*)d_out;
    u64* cbB = (u64*)d_ws;                 // 8192 words
    u64* cbT = cbB + NF * 16 * 64 * 2;     // 8192 words (128 KB of ws total)

    pack_cb_kernel<<<64, 256, 0, stream>>>(cb, cbB, cbT);
    resonator_kernel<<<NB / NRB, 1024, 0, stream>>>(inp, est0, cbB, cbT, out);
}

// Round 13
// 1627.215 us; speedup vs baseline: 1.3883x; 1.0026x over previous
//
#include <hip/hip_runtime.h>
#include <stdint.h>

// Resonator network, b=1024 f=4 v=64 d=2048, 100 iterations.
// All values +-1 -> exact bit arithmetic. Round 13: r12 structure (LDS
// tables, 16 waves = factor x row, 4 rows/block, 256 blocks, hoisted
// ds_read_b128 batches) with the block-wide barrier replaced by PER-ROW
// LDS semaphores: the 4 rows drift out of phase so each SIMD sees mixed
// phases (fills the serial-chain stalls lockstep created). s_conv is
// parity-buffered (race-free under the sem gating: every cross-wave read
// precedes that wave's own sem increment). Per-row independent early exit.
// Micro: __mul24 for cmul*colb (full-rate i24), cndmask outlier terms.

#define NB 1024
#define NF 4
#define ND 2048
#define NW 32            // ND/64 words per row
#define ITERS 100
#define NRB 4            // rows per block

#define OFF_OUT  (NB*NF*ND)
#define OFF_MS   (OFF_OUT + NB*NF)
#define OFF_CONV (OFF_MS + NB*NF)

typedef unsigned long long u64;

// Pack codebooks into the LDS-friendly layout, directly in d_ws:
//  cbB[((j*16+w2)*64 + v)*2 + k] : row-bits word for (j, w=2*w2+k, v)
//  cbT[((j*16+w2)*64 + la)*2 + k]: column mask for (j, d=(2*w2+k)*64+la)
__global__ void pack_cb_kernel(const float* __restrict__ cb,
                               u64* __restrict__ cbB, u64* __restrict__ cbT) {
    const int lane = threadIdx.x & 63;
    const int gw   = (blockIdx.x * (blockDim.x >> 6)) + (threadIdx.x >> 6);
    const int nw   = (gridDim.x * blockDim.x) >> 6;
    for (int idx = gw; idx < NF * 64 * NW; idx += nw) {
        const int j = idx >> 11, v = (idx >> 5) & 63, w = idx & 31;
        const float x = cb[(((j << 6) | v) << 11) + (w << 6) + lane];
        const u64 m = __ballot(x < 0.0f);
        if (lane == 0)
            cbB[(((((j << 4) | (w >> 1)) << 6) | v) << 1) | (w & 1)] = m;
    }
    for (int idx = gw; idx < NF * ND; idx += nw) {
        const int j = idx >> 11, d = idx & 2047;
        const float x = cb[(((j << 6) | lane) << 11) + d];
        const u64 m = __ballot(x < 0.0f);
        const int w = d >> 6, la = d & 63;
        if (lane == 0)
            cbT[(((((j << 4) | (w >> 1)) << 6) | la) << 1) | (w & 1)] = m;
    }
}

// per-word phase-C body
#define PCW(CW, W)                                                           \
    {                                                                        \
        const u64 cw_ = (CW);                                                \
        int t = base + __mul24(cmul, (int)__popcll(cw_));                    \
        t += (int)__popcll(c0 & cw_) << 2;                                   \
        t += (int)__popcll(c1 & cw_) << 3;                                   \
        t += (int)__popcll(c2 & cw_) << 4;                                   \
        t += (int)__popcll(c3 & cw_) << 5;                                   \
        t += (int)__popcll(c4 & cw_) << 6;                                   \
        t += (int)__popcll(c5 & cw_) << 7;                                   \
        t += (int)__popcll(c6 & cw_) << 8;                                   \
        t += (int)__popcll(c7 & cw_) << 9;                                   \
        t += ((cw_ >> ov0) & 1) ? oe0 : 0;                                   \
        t += ((cw_ >> ov1) & 1) ? oe1 : 0;                                   \
        if (nov > 2) {                           /* exact, ~never taken */   \
            u64 m2 = om;                                                     \
            while (m2) {                                                     \
                const int vv = __builtin_ctzll(m2); m2 &= m2 - 1;            \
                t += 4 * __builtin_amdgcn_readlane(ex, vv)                   \
                       * (int)((cw_ >> vv) & 1);                             \
            }                                                                \
        }                                                                    \
        const u64 nww = __ballot(t < 0);                                     \
        if (lane == 0) s_hist[r][nxt][j][W] = nww;                           \
    }

__global__ __launch_bounds__(1024, 2) void resonator_kernel(
    const float* __restrict__ inp, const float* __restrict__ est_init,
    const u64* __restrict__ cbB, const u64* __restrict__ cbT,
    float* __restrict__ out) {
    __shared__ u64 l_cbB[NF * 16 * 64 * 2];   // 64 KB, [j][w2][lane][k]
    __shared__ u64 l_cbT[NF * 16 * 64 * 2];   // 64 KB
    __shared__ u64 s_hist[NRB][3][NF][NW];    // 12 KB, 3-slot ring
    __shared__ u64 s_inp[NRB][NW];            // 1 KB
    __shared__ u64 s_ne[NRB][NF][NW];         // 4 KB
    __shared__ int s_conv[2][NRB][NF];        // parity-buffered flags
    __shared__ int s_sem[NRB];                // per-row semaphore

    const int b    = blockIdx.x;          // 0..255
    const int tid  = threadIdx.x;
    const int wid  = tid >> 6;            // 0..15
    const int lane = tid & 63;
    const int j    = wid & 3;             // factor
    const int r    = wid >> 2;            // row-in-block
    const int row  = (b << 2) + r;

    // ---- copy tables to LDS (one-time) ----
    for (int idx = tid; idx < NF * 16 * 64 * 2; idx += 1024) {
        l_cbB[idx] = cbB[idx];
        l_cbT[idx] = cbT[idx];
    }
    if (tid < NRB) s_sem[tid] = 0;
    // ---- pack input + est_0 ----
    #pragma unroll
    for (int k = 0; k < 8; ++k) {
        const int w = (j << 3) + k;
        const u64 m = __ballot(inp[(row << 11) + (w << 6) + lane] < 0.0f);
        if (lane == 0) s_inp[r][w] = m;
    }
    #pragma unroll 4
    for (int w = 0; w < NW; ++w) {
        const u64 m = __ballot(
            est_init[(((row << 2) | j) << 11) + (w << 6) + lane] < 0.0f);
        if (lane == 0) s_hist[r][0][j][w] = m;
    }
    __syncthreads();      // the only block-wide barrier

    const ulonglong2* tB = (const ulonglong2*)l_cbB + (j << 10) + lane;
    const ulonglong2* tT = (const ulonglong2*)l_cbT + (j << 10) + lane;
    volatile int* vsem = (volatile int*)&s_sem[r];

    int s100 = -1, s99 = -1;
    int cur = 0, nxt = 1, prv = 2;

    for (int it = 0; it < ITERS; ++it) {
        // ne for own (row, factor); row-local LDS, gated by row sync
        if (lane < NW) {
            const u64 X = s_inp[r][lane]
                ^ s_hist[r][cur][0][lane] ^ s_hist[r][cur][1][lane]
                ^ s_hist[r][cur][2][lane] ^ s_hist[r][cur][3][lane];
            s_ne[r][j][lane] = X ^ s_hist[r][cur][j][lane];
        }

        // ---- phase B: pc_v; lane = v; 8-deep hoisted b128 loads ----
        int pc = 0;
        #pragma unroll
        for (int hh = 0; hh < 2; ++hh) {
            ulonglong2 gB[8];
            #pragma unroll
            for (int k = 0; k < 8; ++k)
                gB[k] = tB[((hh << 3) | k) << 6];
            #pragma unroll
            for (int k = 0; k < 8; ++k) {
                const int w2 = (hh << 3) | k;
                const ulonglong2 nn =
                    *(const ulonglong2*)&s_ne[r][j][w2 << 1];
                pc += (int)__popcll(nn.x ^ gB[k].x)
                    + (int)__popcll(nn.y ^ gB[k].y);
            }
        }
        int sp = pc;
        #pragma unroll
        for (int off = 32; off > 0; off >>= 1) sp += __shfl_xor(sp, off);

        // ---- mean-centered exact decomposition ----
        const int mean = sp >> 6;
        const int dev  = pc - mean;
        const int devc = dev < -128 ? -128 : (dev > 127 ? 127 : dev);
        const int ex   = dev - devc;
        const int u    = devc + 128;      // 0..255
        const u64 c0 = __ballot(u & 1),  c1 = __ballot(u & 2);
        const u64 c2 = __ballot(u & 4),  c3 = __ballot(u & 8);
        const u64 c4 = __ballot(u & 16), c5 = __ballot(u & 32);
        const u64 c6 = __ballot(u & 64), c7 = __ballot(u & 128);
        u64 om = __ballot(ex != 0);
        const int nov = (int)__popcll(om);
        int ov0 = 0, ov1 = 0, oe0 = 0, oe1 = 0;
        if (nov > 0) {
            ov0 = __builtin_ctzll(om); om &= om - 1;
            oe0 = 4 * __builtin_amdgcn_readlane(ex, ov0);
            if (nov > 1) {
                ov1 = __builtin_ctzll(om); om &= om - 1;
                oe1 = 4 * __builtin_amdgcn_readlane(ex, ov1);
            }
        }
        const int base = 131072 - 2 * sp;
        const int cmul = 4 * mean - 4608;

        // ---- phase C: lane = d%64; 8-deep hoisted b128 loads ----
        #pragma unroll
        for (int hh = 0; hh < 2; ++hh) {
            ulonglong2 gT[8];
            #pragma unroll
            for (int k = 0; k < 8; ++k)
                gT[k] = tT[((hh << 3) | k) << 6];
            #pragma unroll
            for (int k = 0; k < 8; ++k) {
                const int w2 = (hh << 3) | k;
                PCW(gT[k].x, (w2 << 1))
                PCW(gT[k].y, (w2 << 1) + 1)
            }
        }

        // ---- period<=2 flags (parity slot) ----
        int d1 = 0, d2 = 0;
        if (lane < NW) {
            const u64 a = s_hist[r][nxt][j][lane];
            d1 = (a != s_hist[r][cur][j][lane]);
            d2 = (a != s_hist[r][prv][j][lane]);  // it=0 garbage, guarded
        }
        const u64 b1 = __ballot(d1), b2 = __ballot(d2);
        if (lane == 0)
            s_conv[it & 1][r][j] = (b1 == 0 ? 1 : 0) | (b2 == 0 ? 2 : 0);

        // ---- per-row semaphore sync (replaces block barrier) ----
        __threadfence_block();                    // drain own LDS writes
        if (lane == 0) atomicAdd(&s_sem[r], 1);
        const int tgt = (it + 1) << 2;
        while (*vsem < tgt) __builtin_amdgcn_s_sleep(1);
        __threadfence_block();                    // no hoisting of reads

        // ---- per-row decision ----
        const int p = it & 1;
        const int flr = s_conv[p][r][0] & s_conv[p][r][1]
                      & s_conv[p][r][2] & s_conv[p][r][3];
        if ((flr & 1) || (it >= 1 && (flr & 2))) {
            if (flr & 1) { s100 = nxt; s99 = nxt; }
            else {
                s100 = (((ITERS - it) & 1) == 0) ? cur : nxt;
                s99  = (s100 == nxt) ? cur : nxt;
            }
            break;
        }
        const int t3 = prv; prv = cur; cur = nxt; nxt = t3;
    }
    if (s100 < 0) { s100 = cur; s99 = prv; }   // natural end, post-rotation

    // ---- epilogue, fully row-local (no block sync) ----
    // outcome: argmax_v |sim(est_100, cb)| for (row, factor j)
    int pcO = 0;
    #pragma unroll
    for (int w2 = 0; w2 < 16; ++w2) {
        const ulonglong2 g  = tB[w2 << 6];
        const ulonglong2 hh = *(const ulonglong2*)&s_hist[r][s100][j][w2 << 1];
        pcO += (int)__popcll(hh.x ^ g.x) + (int)__popcll(hh.y ^ g.y);
    }
    const int simF = ND - (pcO << 1);
    const int aF   = simF < 0 ? -simF : simF;
    int key = (aF << 6) | (63 - lane);
    #pragma unroll
    for (int off = 32; off > 0; off >>= 1) {
        const int t1 = __shfl_xor(key, off);
        key = key > t1 ? key : t1;
    }

    // max_sims[-1] = ND - 2*min_v pc on ne(est_99)
    int pc9 = 0;
    #pragma unroll
    for (int w2 = 0; w2 < 16; ++w2) {
        const ulonglong2 g = tB[w2 << 6];
        const int w = w2 << 1;
        const u64 X0 = s_inp[r][w]
            ^ s_hist[r][s99][0][w] ^ s_hist[r][s99][1][w]
            ^ s_hist[r][s99][2][w] ^ s_hist[r][s99][3][w];
        const u64 n0 = X0 ^ s_hist[r][s99][j][w];
        const u64 X1 = s_inp[r][w + 1]
            ^ s_hist[r][s99][0][w + 1] ^ s_hist[r][s99][1][w + 1]
            ^ s_hist[r][s99][2][w + 1] ^ s_hist[r][s99][3][w + 1];
        const u64 n1 = X1 ^ s_hist[r][s99][j][w + 1];
        pc9 += (int)__popcll(n0 ^ g.x) + (int)__popcll(n1 ^ g.y);
    }
    int mn9 = pc9;
    #pragma unroll
    for (int off = 32; off > 0; off >>= 1) {
        const int a1 = __shfl_xor(mn9, off);
        mn9 = mn9 < a1 ? mn9 : a1;
    }
    if (lane == 0) {
        out[OFF_OUT + (row << 2) + j] = (float)(63 - (key & 63));
        out[OFF_MS  + (row << 2) + j] = (float)(ND - 2 * mn9);
    }

    // unpack est_100: wave (r,j) writes its own factor's 2048 floats
    #pragma unroll 4
    for (int k = 0; k < NW; ++k) {
        const u64 wrd = s_hist[r][s100][j][k];
        out[(row << 13) + (j << 11) + (k << 6) + lane] =
            ((wrd >> lane) & 1) ? -1.0f : 1.0f;
    }
    if (b == 0 && tid == 0) out[OFF_CONV] = 99.0f;
}

extern "C" void kernel_launch(void* const* d_in, const int* in_sizes, int n_in,
                              void* d_out, int out_size, void* d_ws, size_t ws_size,
                              hipStream_t stream) {
    const float* inp  = (const float*)d_in[0];
    const float* est0 = (const float*)d_in[1];
    const float* cb   = (const float*)d_in[2];
    float* out = (float*)d_out;
    u64* cbB = (u64*)d_ws;                 // 8192 words
    u64* cbT = cbB + NF * 16 * 64 * 2;     // 8192 words (128 KB of ws total)

    pack_cb_kernel<<<64, 256, 0, stream>>>(cb, cbB, cbT);
    resonator_kernel<<<NB / NRB, 1024, 0, stream>>>(inp, est0, cbB, cbT, out);
}

// Round 14
// 1530.050 us; speedup vs baseline: 1.4765x; 1.0635x over previous
//
#include <hip/hip_runtime.h>
#include <stdint.h>

// Resonator network, b=1024 f=4 v=64 d=2048, 100 iterations.
// All values +-1 -> exact bit arithmetic. Round 14: r13 structure (LDS
// tables, 16 waves = row x factor, per-row semaphore sync, hoisted
// ds_read_b128 batches) with the last instruction diet:
//  (1) branch-free hot phase C: the nov>2 fallback (wave-uniform, ~never)
//      is one outer branch with a cold duplicate, removing 32 scalar
//      branches per wave-iteration from the hot path;
//  (2) static colb: per-word column popcounts are iteration-invariant,
//      precomputed once into 8 packed VGPRs (bfe extract per word).

#define NB 1024
#define NF 4
#define ND 2048
#define NW 32            // ND/64 words per row
#define ITERS 100
#define NRB 4            // rows per block

#define OFF_OUT  (NB*NF*ND)
#define OFF_MS   (OFF_OUT + NB*NF)
#define OFF_CONV (OFF_MS + NB*NF)

typedef unsigned long long u64;

// Pack codebooks into the LDS-friendly layout, directly in d_ws:
//  cbB[((j*16+w2)*64 + v)*2 + k] : row-bits word for (j, w=2*w2+k, v)
//  cbT[((j*16+w2)*64 + la)*2 + k]: column mask for (j, d=(2*w2+k)*64+la)
__global__ void pack_cb_kernel(const float* __restrict__ cb,
                               u64* __restrict__ cbB, u64* __restrict__ cbT) {
    const int lane = threadIdx.x & 63;
    const int gw   = (blockIdx.x * (blockDim.x >> 6)) + (threadIdx.x >> 6);
    const int nw   = (gridDim.x * blockDim.x) >> 6;
    for (int idx = gw; idx < NF * 64 * NW; idx += nw) {
        const int j = idx >> 11, v = (idx >> 5) & 63, w = idx & 31;
        const float x = cb[(((j << 6) | v) << 11) + (w << 6) + lane];
        const u64 m = __ballot(x < 0.0f);
        if (lane == 0)
            cbB[(((((j << 4) | (w >> 1)) << 6) | v) << 1) | (w & 1)] = m;
    }
    for (int idx = gw; idx < NF * ND; idx += nw) {
        const int j = idx >> 11, d = idx & 2047;
        const float x = cb[(((j << 6) | lane) << 11) + d];
        const u64 m = __ballot(x < 0.0f);
        const int w = d >> 6, la = d & 63;
        if (lane == 0)
            cbT[(((((j << 4) | (w >> 1)) << 6) | la) << 1) | (w & 1)] = m;
    }
}

// hot per-word phase-C body (no nov>2 branch)
#define PCW_HOT(CW, W)                                                       \
    {                                                                        \
        const u64 cw_ = (CW);                                                \
        const int colb_ =                                                    \
            (int)((colb_pk[(W) >> 2] >> (((W) & 3) << 3)) & 255u);           \
        int t = base + __mul24(cmul, colb_);                                 \
        t += (int)__popcll(c0 & cw_) << 2;                                   \
        t += (int)__popcll(c1 & cw_) << 3;                                   \
        t += (int)__popcll(c2 & cw_) << 4;                                   \
        t += (int)__popcll(c3 & cw_) << 5;                                   \
        t += (int)__popcll(c4 & cw_) << 6;                                   \
        t += (int)__popcll(c5 & cw_) << 7;                                   \
        t += (int)__popcll(c6 & cw_) << 8;                                   \
        t += (int)__popcll(c7 & cw_) << 9;                                   \
        t += ((cw_ >> ov0) & 1) ? oe0 : 0;                                   \
        t += ((cw_ >> ov1) & 1) ? oe1 : 0;                                   \
        const u64 nww = __ballot(t < 0);                                     \
        if (lane == 0) s_hist[r][nxt][j][W] = nww;                           \
    }

// cold per-word phase-C body (exact >2-outlier fallback, ~never taken)
#define PCW_COLD(CW, W)                                                      \
    {                                                                        \
        const u64 cw_ = (CW);                                                \
        const int colb_ =                                                    \
            (int)((colb_pk[(W) >> 2] >> (((W) & 3) << 3)) & 255u);           \
        int t = base + __mul24(cmul, colb_);                                 \
        t += (int)__popcll(c0 & cw_) << 2;                                   \
        t += (int)__popcll(c1 & cw_) << 3;                                   \
        t += (int)__popcll(c2 & cw_) << 4;                                   \
        t += (int)__popcll(c3 & cw_) << 5;                                   \
        t += (int)__popcll(c4 & cw_) << 6;                                   \
        t += (int)__popcll(c5 & cw_) << 7;                                   \
        t += (int)__popcll(c6 & cw_) << 8;                                   \
        t += (int)__popcll(c7 & cw_) << 9;                                   \
        t += ((cw_ >> ov0) & 1) ? oe0 : 0;                                   \
        t += ((cw_ >> ov1) & 1) ? oe1 : 0;                                   \
        u64 m2 = om;                                                         \
        while (m2) {                                                         \
            const int vv = __builtin_ctzll(m2); m2 &= m2 - 1;                \
            t += 4 * __builtin_amdgcn_readlane(ex, vv)                       \
                   * (int)((cw_ >> vv) & 1);                                 \
        }                                                                    \
        const u64 nww = __ballot(t < 0);                                     \
        if (lane == 0) s_hist[r][nxt][j][W] = nww;                           \
    }

__global__ __launch_bounds__(1024, 2) void resonator_kernel(
    const float* __restrict__ inp, const float* __restrict__ est_init,
    const u64* __restrict__ cbB, const u64* __restrict__ cbT,
    float* __restrict__ out) {
    __shared__ u64 l_cbB[NF * 16 * 64 * 2];   // 64 KB, [j][w2][lane][k]
    __shared__ u64 l_cbT[NF * 16 * 64 * 2];   // 64 KB
    __shared__ u64 s_hist[NRB][3][NF][NW];    // 12 KB, 3-slot ring
    __shared__ u64 s_inp[NRB][NW];            // 1 KB
    __shared__ u64 s_ne[NRB][NF][NW];         // 4 KB
    __shared__ int s_conv[2][NRB][NF];        // parity-buffered flags
    __shared__ int s_sem[NRB];                // per-row semaphore

    const int b    = blockIdx.x;          // 0..255
    const int tid  = threadIdx.x;
    const int wid  = tid >> 6;            // 0..15
    const int lane = tid & 63;
    const int j    = wid & 3;             // factor
    const int r    = wid >> 2;            // row-in-block
    const int row  = (b << 2) + r;

    // ---- copy tables to LDS (one-time) ----
    for (int idx = tid; idx < NF * 16 * 64 * 2; idx += 1024) {
        l_cbB[idx] = cbB[idx];
        l_cbT[idx] = cbT[idx];
    }
    if (tid < NRB) s_sem[tid] = 0;
    // ---- pack input + est_0 ----
    #pragma unroll
    for (int k = 0; k < 8; ++k) {
        const int w = (j << 3) + k;
        const u64 m = __ballot(inp[(row << 11) + (w << 6) + lane] < 0.0f);
        if (lane == 0) s_inp[r][w] = m;
    }
    #pragma unroll 4
    for (int w = 0; w < NW; ++w) {
        const u64 m = __ballot(
            est_init[(((row << 2) | j) << 11) + (w << 6) + lane] < 0.0f);
        if (lane == 0) s_hist[r][0][j][w] = m;
    }
    __syncthreads();      // the only block-wide barrier

    const ulonglong2* tB = (const ulonglong2*)l_cbB + (j << 10) + lane;
    const ulonglong2* tT = (const ulonglong2*)l_cbT + (j << 10) + lane;
    volatile int* vsem = (volatile int*)&s_sem[r];

    // ---- static per-lane column popcounts, packed u8x4 (8 VGPRs) ----
    uint32_t colb_pk[8];
    #pragma unroll
    for (int w2 = 0; w2 < 16; w2 += 2) {
        const ulonglong2 gA = tT[w2 << 6];
        const ulonglong2 gB = tT[(w2 + 1) << 6];
        colb_pk[w2 >> 1] = (uint32_t)__popcll(gA.x)
                         | ((uint32_t)__popcll(gA.y) << 8)
                         | ((uint32_t)__popcll(gB.x) << 16)
                         | ((uint32_t)__popcll(gB.y) << 24);
    }

    int s100 = -1, s99 = -1;
    int cur = 0, nxt = 1, prv = 2;

    for (int it = 0; it < ITERS; ++it) {
        // ne for own (row, factor); row-local LDS, gated by row sync
        if (lane < NW) {
            const u64 X = s_inp[r][lane]
                ^ s_hist[r][cur][0][lane] ^ s_hist[r][cur][1][lane]
                ^ s_hist[r][cur][2][lane] ^ s_hist[r][cur][3][lane];
            s_ne[r][j][lane] = X ^ s_hist[r][cur][j][lane];
        }

        // ---- phase B: pc_v; lane = v; 8-deep hoisted b128 loads ----
        int pc = 0;
        #pragma unroll
        for (int hh = 0; hh < 2; ++hh) {
            ulonglong2 gB[8];
            #pragma unroll
            for (int k = 0; k < 8; ++k)
                gB[k] = tB[((hh << 3) | k) << 6];
            #pragma unroll
            for (int k = 0; k < 8; ++k) {
                const int w2 = (hh << 3) | k;
                const ulonglong2 nn =
                    *(const ulonglong2*)&s_ne[r][j][w2 << 1];
                pc += (int)__popcll(nn.x ^ gB[k].x)
                    + (int)__popcll(nn.y ^ gB[k].y);
            }
        }
        int sp = pc;
        #pragma unroll
        for (int off = 32; off > 0; off >>= 1) sp += __shfl_xor(sp, off);

        // ---- mean-centered exact decomposition ----
        const int mean = sp >> 6;
        const int dev  = pc - mean;
        const int devc = dev < -128 ? -128 : (dev > 127 ? 127 : dev);
        const int ex   = dev - devc;
        const int u    = devc + 128;      // 0..255
        const u64 c0 = __ballot(u & 1),  c1 = __ballot(u & 2);
        const u64 c2 = __ballot(u & 4),  c3 = __ballot(u & 8);
        const u64 c4 = __ballot(u & 16), c5 = __ballot(u & 32);
        const u64 c6 = __ballot(u & 64), c7 = __ballot(u & 128);
        u64 om = __ballot(ex != 0);
        const int nov = (int)__popcll(om);
        int ov0 = 0, ov1 = 0, oe0 = 0, oe1 = 0;
        if (nov > 0) {
            ov0 = __builtin_ctzll(om); om &= om - 1;
            oe0 = 4 * __builtin_amdgcn_readlane(ex, ov0);
            if (nov > 1) {
                ov1 = __builtin_ctzll(om); om &= om - 1;
                oe1 = 4 * __builtin_amdgcn_readlane(ex, ov1);
            }
        }
        const int base = 131072 - 2 * sp;
        const int cmul = 4 * mean - 4608;

        // ---- phase C: lane = d%64; 8-deep hoisted b128 loads ----
        if (__builtin_expect(nov <= 2, 1)) {      // hot: branch-free body
            #pragma unroll
            for (int hh = 0; hh < 2; ++hh) {
                ulonglong2 gT[8];
                #pragma unroll
                for (int k = 0; k < 8; ++k)
                    gT[k] = tT[((hh << 3) | k) << 6];
                #pragma unroll
                for (int k = 0; k < 8; ++k) {
                    const int w2 = (hh << 3) | k;
                    PCW_HOT(gT[k].x, (w2 << 1))
                    PCW_HOT(gT[k].y, (w2 << 1) + 1)
                }
            }
        } else {                                   // cold: exact fallback
            #pragma unroll
            for (int hh = 0; hh < 2; ++hh) {
                ulonglong2 gT[8];
                #pragma unroll
                for (int k = 0; k < 8; ++k)
                    gT[k] = tT[((hh << 3) | k) << 6];
                #pragma unroll
                for (int k = 0; k < 8; ++k) {
                    const int w2 = (hh << 3) | k;
                    PCW_COLD(gT[k].x, (w2 << 1))
                    PCW_COLD(gT[k].y, (w2 << 1) + 1)
                }
            }
        }

        // ---- period<=2 flags (parity slot) ----
        int d1 = 0, d2 = 0;
        if (lane < NW) {
            const u64 a = s_hist[r][nxt][j][lane];
            d1 = (a != s_hist[r][cur][j][lane]);
            d2 = (a != s_hist[r][prv][j][lane]);  // it=0 garbage, guarded
        }
        const u64 b1 = __ballot(d1), b2 = __ballot(d2);
        if (lane == 0)
            s_conv[it & 1][r][j] = (b1 == 0 ? 1 : 0) | (b2 == 0 ? 2 : 0);

        // ---- per-row semaphore sync ----
        __threadfence_block();                    // drain own LDS writes
        if (lane == 0) atomicAdd(&s_sem[r], 1);
        const int tgt = (it + 1) << 2;
        while (*vsem < tgt) __builtin_amdgcn_s_sleep(1);
        __threadfence_block();                    // no hoisting of reads

        // ---- per-row decision ----
        const int p = it & 1;
        const int flr = s_conv[p][r][0] & s_conv[p][r][1]
                      & s_conv[p][r][2] & s_conv[p][r][3];
        if ((flr & 1) || (it >= 1 && (flr & 2))) {
            if (flr & 1) { s100 = nxt; s99 = nxt; }
            else {
                s100 = (((ITERS - it) & 1) == 0) ? cur : nxt;
                s99  = (s100 == nxt) ? cur : nxt;
            }
            break;
        }
        const int t3 = prv; prv = cur; cur = nxt; nxt = t3;
    }
    if (s100 < 0) { s100 = cur; s99 = prv; }   // natural end, post-rotation

    // ---- epilogue, fully row-local ----
    int pcO = 0;
    #pragma unroll
    for (int w2 = 0; w2 < 16; ++w2) {
        const ulonglong2 g  = tB[w2 << 6];
        const ulonglong2 hh = *(const ulonglong2*)&s_hist[r][s100][j][w2 << 1];
        pcO += (int)__popcll(hh.x ^ g.x) + (int)__popcll(hh.y ^ g.y);
    }
    const int simF = ND - (pcO << 1);
    const int aF   = simF < 0 ? -simF : simF;
    int key = (aF << 6) | (63 - lane);
    #pragma unroll
    for (int off = 32; off > 0; off >>= 1) {
        const int t1 = __shfl_xor(key, off);
        key = key > t1 ? key : t1;
    }

    // max_sims[-1] = ND - 2*min_v pc on ne(est_99)
    int pc9 = 0;
    #pragma unroll
    for (int w2 = 0; w2 < 16; ++w2) {
        const ulonglong2 g = tB[w2 << 6];
        const int w = w2 << 1;
        const u64 X0 = s_inp[r][w]
            ^ s_hist[r][s99][0][w] ^ s_hist[r][s99][1][w]
            ^ s_hist[r][s99][2][w] ^ s_hist[r][s99][3][w];
        const u64 n0 = X0 ^ s_hist[r][s99][j][w];
        const u64 X1 = s_inp[r][w + 1]
            ^ s_hist[r][s99][0][w + 1] ^ s_hist[r][s99][1][w + 1]
            ^ s_hist[r][s99][2][w + 1] ^ s_hist[r][s99][3][w + 1];
        const u64 n1 = X1 ^ s_hist[r][s99][j][w + 1];
        pc9 += (int)__popcll(n0 ^ g.x) + (int)__popcll(n1 ^ g.y);
    }
    int mn9 = pc9;
    #pragma unroll
    for (int off = 32; off > 0; off >>= 1) {
        const int a1 = __shfl_xor(mn9, off);
        mn9 = mn9 < a1 ? mn9 : a1;
    }
    if (lane == 0) {
        out[OFF_OUT + (row << 2) + j] = (float)(63 - (key & 63));
        out[OFF_MS  + (row << 2) + j] = (float)(ND - 2 * mn9);
    }

    // unpack est_100: wave (r,j) writes its own factor's 2048 floats
    #pragma unroll 4
    for (int k = 0; k < NW; ++k) {
        const u64 wrd = s_hist[r][s100][j][k];
        out[(row << 13) + (j << 11) + (k << 6) + lane] =
            ((wrd >> lane) & 1) ? -1.0f : 1.0f;
    }
    if (b == 0 && tid == 0) out[OFF_CONV] = 99.0f;
}

extern "C" void kernel_launch(void* const* d_in, const int* in_sizes, int n_in,
                              void* d_out, int out_size, void* d_ws, size_t ws_size,
                              hipStream_t stream) {
    const float* inp  = (const float*)d_in[0];
    const float* est0 = (const float*)d_in[1];
    const float* cb   = (const float*)d_in[2];
    float* out = (float*)d_out;
    u64* cbB = (u64*)d_ws;                 // 8192 words
    u64* cbT = cbB + NF * 16 * 64 * 2;     // 8192 words (128 KB of ws total)

    pack_cb_kernel<<<64, 256, 0, stream>>>(cb, cbB, cbT);
    resonator_kernel<<<NB / NRB, 1024, 0, stream>>>(inp, est0, cbB, cbT, out);
}

// Round 15
// 1422.501 us; speedup vs baseline: 1.5881x; 1.0756x over previous
//
#include <hip/hip_runtime.h>
#include <stdint.h>

// Resonator network, b=1024 f=4 v=64 d=2048, 100 iterations.
// All values +-1 -> exact bit arithmetic. Round 15: r14 structure with the
// plane count cut 8 -> 7 (exact): clip dev at +-64 (C=64), u = devc+64 in
// [0,128) = 7 bit-planes, cmul = 4*mean - 4352. Chaotic dev sigma ~23 so
// +-64 = 2.8 sigma; converged winner lanes were already outliers at +-128
// and stay in the 2-outlier hot path. Saves ~5 VALU x 32 words per iter.

#define NB 1024
#define NF 4
#define ND 2048
#define NW 32            // ND/64 words per row
#define ITERS 100
#define NRB 4            // rows per block

#define OFF_OUT  (NB*NF*ND)
#define OFF_MS   (OFF_OUT + NB*NF)
#define OFF_CONV (OFF_MS + NB*NF)

typedef unsigned long long u64;

// Pack codebooks into the LDS-friendly layout, directly in d_ws:
//  cbB[((j*16+w2)*64 + v)*2 + k] : row-bits word for (j, w=2*w2+k, v)
//  cbT[((j*16+w2)*64 + la)*2 + k]: column mask for (j, d=(2*w2+k)*64+la)
__global__ void pack_cb_kernel(const float* __restrict__ cb,
                               u64* __restrict__ cbB, u64* __restrict__ cbT) {
    const int lane = threadIdx.x & 63;
    const int gw   = (blockIdx.x * (blockDim.x >> 6)) + (threadIdx.x >> 6);
    const int nw   = (gridDim.x * blockDim.x) >> 6;
    for (int idx = gw; idx < NF * 64 * NW; idx += nw) {
        const int j = idx >> 11, v = (idx >> 5) & 63, w = idx & 31;
        const float x = cb[(((j << 6) | v) << 11) + (w << 6) + lane];
        const u64 m = __ballot(x < 0.0f);
        if (lane == 0)
            cbB[(((((j << 4) | (w >> 1)) << 6) | v) << 1) | (w & 1)] = m;
    }
    for (int idx = gw; idx < NF * ND; idx += nw) {
        const int j = idx >> 11, d = idx & 2047;
        const float x = cb[(((j << 6) | lane) << 11) + d];
        const u64 m = __ballot(x < 0.0f);
        const int w = d >> 6, la = d & 63;
        if (lane == 0)
            cbT[(((((j << 4) | (w >> 1)) << 6) | la) << 1) | (w & 1)] = m;
    }
}

// hot per-word phase-C body (7 planes, 2 outliers, no nov>2 branch)
#define PCW_HOT(CW, W)                                                       \
    {                                                                        \
        const u64 cw_ = (CW);                                                \
        const int colb_ =                                                    \
            (int)((colb_pk[(W) >> 2] >> (((W) & 3) << 3)) & 255u);           \
        int t = base + __mul24(cmul, colb_);                                 \
        t += (int)__popcll(c0 & cw_) << 2;                                   \
        t += (int)__popcll(c1 & cw_) << 3;                                   \
        t += (int)__popcll(c2 & cw_) << 4;                                   \
        t += (int)__popcll(c3 & cw_) << 5;                                   \
        t += (int)__popcll(c4 & cw_) << 6;                                   \
        t += (int)__popcll(c5 & cw_) << 7;                                   \
        t += (int)__popcll(c6 & cw_) << 8;                                   \
        t += ((cw_ >> ov0) & 1) ? oe0 : 0;                                   \
        t += ((cw_ >> ov1) & 1) ? oe1 : 0;                                   \
        const u64 nww = __ballot(t < 0);                                     \
        if (lane == 0) s_hist[r][nxt][j][W] = nww;                           \
    }

// cold per-word phase-C body (exact >2-outlier fallback)
#define PCW_COLD(CW, W)                                                      \
    {                                                                        \
        const u64 cw_ = (CW);                                                \
        const int colb_ =                                                    \
            (int)((colb_pk[(W) >> 2] >> (((W) & 3) << 3)) & 255u);           \
        int t = base + __mul24(cmul, colb_);                                 \
        t += (int)__popcll(c0 & cw_) << 2;                                   \
        t += (int)__popcll(c1 & cw_) << 3;                                   \
        t += (int)__popcll(c2 & cw_) << 4;                                   \
        t += (int)__popcll(c3 & cw_) << 5;                                   \
        t += (int)__popcll(c4 & cw_) << 6;                                   \
        t += (int)__popcll(c5 & cw_) << 7;                                   \
        t += (int)__popcll(c6 & cw_) << 8;                                   \
        t += ((cw_ >> ov0) & 1) ? oe0 : 0;                                   \
        t += ((cw_ >> ov1) & 1) ? oe1 : 0;                                   \
        u64 m2 = om;                                                         \
        while (m2) {                                                         \
            const int vv = __builtin_ctzll(m2); m2 &= m2 - 1;                \
            t += 4 * __builtin_amdgcn_readlane(ex, vv)                       \
                   * (int)((cw_ >> vv) & 1);                                 \
        }                                                                    \
        const u64 nww = __ballot(t < 0);                                     \
        if (lane == 0) s_hist[r][nxt][j][W] = nww;                           \
    }

__global__ __launch_bounds__(1024, 2) void resonator_kernel(
    const float* __restrict__ inp, const float* __restrict__ est_init,
    const u64* __restrict__ cbB, const u64* __restrict__ cbT,
    float* __restrict__ out) {
    __shared__ u64 l_cbB[NF * 16 * 64 * 2];   // 64 KB, [j][w2][lane][k]
    __shared__ u64 l_cbT[NF * 16 * 64 * 2];   // 64 KB
    __shared__ u64 s_hist[NRB][3][NF][NW];    // 12 KB, 3-slot ring
    __shared__ u64 s_inp[NRB][NW];            // 1 KB
    __shared__ u64 s_ne[NRB][NF][NW];         // 4 KB
    __shared__ int s_conv[2][NRB][NF];        // parity-buffered flags
    __shared__ int s_sem[NRB];                // per-row semaphore

    const int b    = blockIdx.x;          // 0..255
    const int tid  = threadIdx.x;
    const int wid  = tid >> 6;            // 0..15
    const int lane = tid & 63;
    const int j    = wid & 3;             // factor
    const int r    = wid >> 2;            // row-in-block
    const int row  = (b << 2) + r;

    // ---- copy tables to LDS (one-time) ----
    for (int idx = tid; idx < NF * 16 * 64 * 2; idx += 1024) {
        l_cbB[idx] = cbB[idx];
        l_cbT[idx] = cbT[idx];
    }
    if (tid < NRB) s_sem[tid] = 0;
    // ---- pack input + est_0 ----
    #pragma unroll
    for (int k = 0; k < 8; ++k) {
        const int w = (j << 3) + k;
        const u64 m = __ballot(inp[(row << 11) + (w << 6) + lane] < 0.0f);
        if (lane == 0) s_inp[r][w] = m;
    }
    #pragma unroll 4
    for (int w = 0; w < NW; ++w) {
        const u64 m = __ballot(
            est_init[(((row << 2) | j) << 11) + (w << 6) + lane] < 0.0f);
        if (lane == 0) s_hist[r][0][j][w] = m;
    }
    __syncthreads();      // the only block-wide barrier

    const ulonglong2* tB = (const ulonglong2*)l_cbB + (j << 10) + lane;
    const ulonglong2* tT = (const ulonglong2*)l_cbT + (j << 10) + lane;
    volatile int* vsem = (volatile int*)&s_sem[r];

    // ---- static per-lane column popcounts, packed u8x4 (8 VGPRs) ----
    uint32_t colb_pk[8];
    #pragma unroll
    for (int w2 = 0; w2 < 16; w2 += 2) {
        const ulonglong2 gA = tT[w2 << 6];
        const ulonglong2 gB = tT[(w2 + 1) << 6];
        colb_pk[w2 >> 1] = (uint32_t)__popcll(gA.x)
                         | ((uint32_t)__popcll(gA.y) << 8)
                         | ((uint32_t)__popcll(gB.x) << 16)
                         | ((uint32_t)__popcll(gB.y) << 24);
    }

    int s100 = -1, s99 = -1;
    int cur = 0, nxt = 1, prv = 2;

    for (int it = 0; it < ITERS; ++it) {
        // ne for own (row, factor); row-local LDS, gated by row sync
        if (lane < NW) {
            const u64 X = s_inp[r][lane]
                ^ s_hist[r][cur][0][lane] ^ s_hist[r][cur][1][lane]
                ^ s_hist[r][cur][2][lane] ^ s_hist[r][cur][3][lane];
            s_ne[r][j][lane] = X ^ s_hist[r][cur][j][lane];
        }

        // ---- phase B: pc_v; lane = v; 8-deep hoisted b128 loads ----
        int pc = 0;
        #pragma unroll
        for (int hh = 0; hh < 2; ++hh) {
            ulonglong2 gB[8];
            #pragma unroll
            for (int k = 0; k < 8; ++k)
                gB[k] = tB[((hh << 3) | k) << 6];
            #pragma unroll
            for (int k = 0; k < 8; ++k) {
                const int w2 = (hh << 3) | k;
                const ulonglong2 nn =
                    *(const ulonglong2*)&s_ne[r][j][w2 << 1];
                pc += (int)__popcll(nn.x ^ gB[k].x)
                    + (int)__popcll(nn.y ^ gB[k].y);
            }
        }
        int sp = pc;
        #pragma unroll
        for (int off = 32; off > 0; off >>= 1) sp += __shfl_xor(sp, off);

        // ---- mean-centered exact decomposition, 7-bit clip ----
        const int mean = sp >> 6;
        const int dev  = pc - mean;
        const int devc = dev < -64 ? -64 : (dev > 63 ? 63 : dev);
        const int ex   = dev - devc;
        const int u    = devc + 64;       // 0..127, 7 planes
        const u64 c0 = __ballot(u & 1),  c1 = __ballot(u & 2);
        const u64 c2 = __ballot(u & 4),  c3 = __ballot(u & 8);
        const u64 c4 = __ballot(u & 16), c5 = __ballot(u & 32);
        const u64 c6 = __ballot(u & 64);
        u64 om = __ballot(ex != 0);
        const int nov = (int)__popcll(om);
        int ov0 = 0, ov1 = 0, oe0 = 0, oe1 = 0;
        if (nov > 0) {
            ov0 = __builtin_ctzll(om); om &= om - 1;
            oe0 = 4 * __builtin_amdgcn_readlane(ex, ov0);
            if (nov > 1) {
                ov1 = __builtin_ctzll(om); om &= om - 1;
                oe1 = 4 * __builtin_amdgcn_readlane(ex, ov1);
            }
        }
        const int base = 131072 - 2 * sp;
        const int cmul = 4 * mean - 4352;      // C=64 derivation

        // ---- phase C: lane = d%64; 8-deep hoisted b128 loads ----
        if (__builtin_expect(nov <= 2, 1)) {      // hot: branch-free body
            #pragma unroll
            for (int hh = 0; hh < 2; ++hh) {
                ulonglong2 gT[8];
                #pragma unroll
                for (int k = 0; k < 8; ++k)
                    gT[k] = tT[((hh << 3) | k) << 6];
                #pragma unroll
                for (int k = 0; k < 8; ++k) {
                    const int w2 = (hh << 3) | k;
                    PCW_HOT(gT[k].x, (w2 << 1))
                    PCW_HOT(gT[k].y, (w2 << 1) + 1)
                }
            }
        } else {                                   // cold: exact fallback
            #pragma unroll
            for (int hh = 0; hh < 2; ++hh) {
                ulonglong2 gT[8];
                #pragma unroll
                for (int k = 0; k < 8; ++k)
                    gT[k] = tT[((hh << 3) | k) << 6];
                #pragma unroll
                for (int k = 0; k < 8; ++k) {
                    const int w2 = (hh << 3) | k;
                    PCW_COLD(gT[k].x, (w2 << 1))
                    PCW_COLD(gT[k].y, (w2 << 1) + 1)
                }
            }
        }

        // ---- period<=2 flags (parity slot) ----
        int d1 = 0, d2 = 0;
        if (lane < NW) {
            const u64 a = s_hist[r][nxt][j][lane];
            d1 = (a != s_hist[r][cur][j][lane]);
            d2 = (a != s_hist[r][prv][j][lane]);  // it=0 garbage, guarded
        }
        const u64 b1 = __ballot(d1), b2 = __ballot(d2);
        if (lane == 0)
            s_conv[it & 1][r][j] = (b1 == 0 ? 1 : 0) | (b2 == 0 ? 2 : 0);

        // ---- per-row semaphore sync ----
        __threadfence_block();                    // drain own LDS writes
        if (lane == 0) atomicAdd(&s_sem[r], 1);
        const int tgt = (it + 1) << 2;
        while (*vsem < tgt) __builtin_amdgcn_s_sleep(1);
        __threadfence_block();                    // no hoisting of reads

        // ---- per-row decision ----
        const int p = it & 1;
        const int flr = s_conv[p][r][0] & s_conv[p][r][1]
                      & s_conv[p][r][2] & s_conv[p][r][3];
        if ((flr & 1) || (it >= 1 && (flr & 2))) {
            if (flr & 1) { s100 = nxt; s99 = nxt; }
            else {
                s100 = (((ITERS - it) & 1) == 0) ? cur : nxt;
                s99  = (s100 == nxt) ? cur : nxt;
            }
            break;
        }
        const int t3 = prv; prv = cur; cur = nxt; nxt = t3;
    }
    if (s100 < 0) { s100 = cur; s99 = prv; }   // natural end, post-rotation

    // ---- epilogue, fully row-local ----
    int pcO = 0;
    #pragma unroll
    for (int w2 = 0; w2 < 16; ++w2) {
        const ulonglong2 g  = tB[w2 << 6];
        const ulonglong2 hh = *(const ulonglong2*)&s_hist[r][s100][j][w2 << 1];
        pcO += (int)__popcll(hh.x ^ g.x) + (int)__popcll(hh.y ^ g.y);
    }
    const int simF = ND - (pcO << 1);
    const int aF   = simF < 0 ? -simF : simF;
    int key = (aF << 6) | (63 - lane);
    #pragma unroll
    for (int off = 32; off > 0; off >>= 1) {
        const int t1 = __shfl_xor(key, off);
        key = key > t1 ? key : t1;
    }

    // max_sims[-1] = ND - 2*min_v pc on ne(est_99)
    int pc9 = 0;
    #pragma unroll
    for (int w2 = 0; w2 < 16; ++w2) {
        const ulonglong2 g = tB[w2 << 6];
        const int w = w2 << 1;
        const u64 X0 = s_inp[r][w]
            ^ s_hist[r][s99][0][w] ^ s_hist[r][s99][1][w]
            ^ s_hist[r][s99][2][w] ^ s_hist[r][s99][3][w];
        const u64 n0 = X0 ^ s_hist[r][s99][j][w];
        const u64 X1 = s_inp[r][w + 1]
            ^ s_hist[r][s99][0][w + 1] ^ s_hist[r][s99][1][w + 1]
            ^ s_hist[r][s99][2][w + 1] ^ s_hist[r][s99][3][w + 1];
        const u64 n1 = X1 ^ s_hist[r][s99][j][w + 1];
        pc9 += (int)__popcll(n0 ^ g.x) + (int)__popcll(n1 ^ g.y);
    }
    int mn9 = pc9;
    #pragma unroll
    for (int off = 32; off > 0; off >>= 1) {
        const int a1 = __shfl_xor(mn9, off);
        mn9 = mn9 < a1 ? mn9 : a1;
    }
    if (lane == 0) {
        out[OFF_OUT + (row << 2) + j] = (float)(63 - (key & 63));
        out[OFF_MS  + (row << 2) + j] = (float)(ND - 2 * mn9);
    }

    // unpack est_100: wave (r,j) writes its own factor's 2048 floats
    #pragma unroll 4
    for (int k = 0; k < NW; ++k) {
        const u64 wrd = s_hist[r][s100][j][k];
        out[(row << 13) + (j << 11) + (k << 6) + lane] =
            ((wrd >> lane) & 1) ? -1.0f : 1.0f;
    }
    if (b == 0 && tid == 0) out[OFF_CONV] = 99.0f;
}

extern "C" void kernel_launch(void* const* d_in, const int* in_sizes, int n_in,
                              void* d_out, int out_size, void* d_ws, size_t ws_size,
                              hipStream_t stream) {
    const float* inp  = (const float*)d_in[0];
    const float* est0 = (const float*)d_in[1];
    const float* cb   = (const float*)d_in[2];
    float* out = (float*)d_out;
    u64* cbB = (u64*)d_ws;                 // 8192 words
    u64* cbT = cbB + NF * 16 * 64 * 2;     // 8192 words (128 KB of ws total)

    pack_cb_kernel<<<64, 256, 0, stream>>>(cb, cbB, cbT);
    resonator_kernel<<<NB / NRB, 1024, 0, stream>>>(inp, est0, cbB, cbT, out);
}

// Round 16
// 1399.040 us; speedup vs baseline: 1.6147x; 1.0168x over previous
//
#include <hip/hip_runtime.h>
#include <stdint.h>

// Resonator network, b=1024 f=4 v=64 d=2048, 100 iterations.
// All values +-1 -> exact bit arithmetic. Round 16: r15 structure with two
// overhead cuts: (1) phase-C LDS writes deferred -- 32 ballot results are
// collected in registers and written in ONE exec-guarded block of 16
// ds_write_b128 (was 32 interleaved exec-toggled writes, ~190 inst);
// (2) the sum reduce uses DPP (row_shr 1/2/4/8 + row_bcast 15/31 +
// readlane 63, VALU pipe, ~60cyc) instead of 6 ds_swizzle shuffles
// (~360cyc serial at the head of every iteration).

#define NB 1024
#define NF 4
#define ND 2048
#define NW 32            // ND/64 words per row
#define ITERS 100
#define NRB 4            // rows per block

#define OFF_OUT  (NB*NF*ND)
#define OFF_MS   (OFF_OUT + NB*NF)
#define OFF_CONV (OFF_MS + NB*NF)

typedef unsigned long long u64;

// Pack codebooks into the LDS-friendly layout, directly in d_ws:
//  cbB[((j*16+w2)*64 + v)*2 + k] : row-bits word for (j, w=2*w2+k, v)
//  cbT[((j*16+w2)*64 + la)*2 + k]: column mask for (j, d=(2*w2+k)*64+la)
__global__ void pack_cb_kernel(const float* __restrict__ cb,
                               u64* __restrict__ cbB, u64* __restrict__ cbT) {
    const int lane = threadIdx.x & 63;
    const int gw   = (blockIdx.x * (blockDim.x >> 6)) + (threadIdx.x >> 6);
    const int nw   = (gridDim.x * blockDim.x) >> 6;
    for (int idx = gw; idx < NF * 64 * NW; idx += nw) {
        const int j = idx >> 11, v = (idx >> 5) & 63, w = idx & 31;
        const float x = cb[(((j << 6) | v) << 11) + (w << 6) + lane];
        const u64 m = __ballot(x < 0.0f);
        if (lane == 0)
            cbB[(((((j << 4) | (w >> 1)) << 6) | v) << 1) | (w & 1)] = m;
    }
    for (int idx = gw; idx < NF * ND; idx += nw) {
        const int j = idx >> 11, d = idx & 2047;
        const float x = cb[(((j << 6) | lane) << 11) + d];
        const u64 m = __ballot(x < 0.0f);
        const int w = d >> 6, la = d & 63;
        if (lane == 0)
            cbT[(((((j << 4) | (w >> 1)) << 6) | la) << 1) | (w & 1)] = m;
    }
}

// canonical GCN wave64 sum via DPP; result broadcast via readlane(63)
__device__ __forceinline__ int wave_sum_dpp(int x) {
    x += __builtin_amdgcn_update_dpp(0, x, 0x111, 0xf, 0xf, true); // shr:1
    x += __builtin_amdgcn_update_dpp(0, x, 0x112, 0xf, 0xf, true); // shr:2
    x += __builtin_amdgcn_update_dpp(0, x, 0x114, 0xf, 0xf, true); // shr:4
    x += __builtin_amdgcn_update_dpp(0, x, 0x118, 0xf, 0xf, true); // shr:8
    x += __builtin_amdgcn_update_dpp(0, x, 0x142, 0xa, 0xf, true); // bcast15
    x += __builtin_amdgcn_update_dpp(0, x, 0x143, 0xc, 0xf, true); // bcast31
    return __builtin_amdgcn_readlane(x, 63);
}

// hot per-word phase-C body (7 planes, 2 outliers) -- result kept in nws[]
#define PCW_HOT(CW, W)                                                       \
    {                                                                        \
        const u64 cw_ = (CW);                                                \
        const int colb_ =                                                    \
            (int)((colb_pk[(W) >> 2] >> (((W) & 3) << 3)) & 255u);           \
        int t = base + __mul24(cmul, colb_);                                 \
        t += (int)__popcll(c0 & cw_) << 2;                                   \
        t += (int)__popcll(c1 & cw_) << 3;                                   \
        t += (int)__popcll(c2 & cw_) << 4;                                   \
        t += (int)__popcll(c3 & cw_) << 5;                                   \
        t += (int)__popcll(c4 & cw_) << 6;                                   \
        t += (int)__popcll(c5 & cw_) << 7;                                   \
        t += (int)__popcll(c6 & cw_) << 8;                                   \
        t += ((cw_ >> ov0) & 1) ? oe0 : 0;                                   \
        t += ((cw_ >> ov1) & 1) ? oe1 : 0;                                   \
        nws[(W)] = __ballot(t < 0);                                          \
    }

// cold per-word phase-C body (exact >2-outlier fallback)
#define PCW_COLD(CW, W)                                                      \
    {                                                                        \
        const u64 cw_ = (CW);                                                \
        const int colb_ =                                                    \
            (int)((colb_pk[(W) >> 2] >> (((W) & 3) << 3)) & 255u);           \
        int t = base + __mul24(cmul, colb_);                                 \
        t += (int)__popcll(c0 & cw_) << 2;                                   \
        t += (int)__popcll(c1 & cw_) << 3;                                   \
        t += (int)__popcll(c2 & cw_) << 4;                                   \
        t += (int)__popcll(c3 & cw_) << 5;                                   \
        t += (int)__popcll(c4 & cw_) << 6;                                   \
        t += (int)__popcll(c5 & cw_) << 7;                                   \
        t += (int)__popcll(c6 & cw_) << 8;                                   \
        t += ((cw_ >> ov0) & 1) ? oe0 : 0;                                   \
        t += ((cw_ >> ov1) & 1) ? oe1 : 0;                                   \
        u64 m2 = om;                                                         \
        while (m2) {                                                         \
            const int vv = __builtin_ctzll(m2); m2 &= m2 - 1;                \
            t += 4 * __builtin_amdgcn_readlane(ex, vv)                       \
                   * (int)((cw_ >> vv) & 1);                                 \
        }                                                                    \
        nws[(W)] = __ballot(t < 0);                                          \
    }

__global__ __launch_bounds__(1024, 2) void resonator_kernel(
    const float* __restrict__ inp, const float* __restrict__ est_init,
    const u64* __restrict__ cbB, const u64* __restrict__ cbT,
    float* __restrict__ out) {
    __shared__ u64 l_cbB[NF * 16 * 64 * 2];   // 64 KB, [j][w2][lane][k]
    __shared__ u64 l_cbT[NF * 16 * 64 * 2];   // 64 KB
    __shared__ u64 s_hist[NRB][3][NF][NW];    // 12 KB, 3-slot ring
    __shared__ u64 s_inp[NRB][NW];            // 1 KB
    __shared__ u64 s_ne[NRB][NF][NW];         // 4 KB
    __shared__ int s_conv[2][NRB][NF];        // parity-buffered flags
    __shared__ int s_sem[NRB];                // per-row semaphore

    const int b    = blockIdx.x;          // 0..255
    const int tid  = threadIdx.x;
    const int wid  = tid >> 6;            // 0..15
    const int lane = tid & 63;
    const int j    = wid & 3;             // factor
    const int r    = wid >> 2;            // row-in-block
    const int row  = (b << 2) + r;

    // ---- copy tables to LDS (one-time) ----
    for (int idx = tid; idx < NF * 16 * 64 * 2; idx += 1024) {
        l_cbB[idx] = cbB[idx];
        l_cbT[idx] = cbT[idx];
    }
    if (tid < NRB) s_sem[tid] = 0;
    // ---- pack input + est_0 ----
    #pragma unroll
    for (int k = 0; k < 8; ++k) {
        const int w = (j << 3) + k;
        const u64 m = __ballot(inp[(row << 11) + (w << 6) + lane] < 0.0f);
        if (lane == 0) s_inp[r][w] = m;
    }
    #pragma unroll 4
    for (int w = 0; w < NW; ++w) {
        const u64 m = __ballot(
            est_init[(((row << 2) | j) << 11) + (w << 6) + lane] < 0.0f);
        if (lane == 0) s_hist[r][0][j][w] = m;
    }
    __syncthreads();      // the only block-wide barrier

    const ulonglong2* tB = (const ulonglong2*)l_cbB + (j << 10) + lane;
    const ulonglong2* tT = (const ulonglong2*)l_cbT + (j << 10) + lane;
    volatile int* vsem = (volatile int*)&s_sem[r];

    // ---- static per-lane column popcounts, packed u8x4 (8 VGPRs) ----
    uint32_t colb_pk[8];
    #pragma unroll
    for (int w2 = 0; w2 < 16; w2 += 2) {
        const ulonglong2 gA = tT[w2 << 6];
        const ulonglong2 gB = tT[(w2 + 1) << 6];
        colb_pk[w2 >> 1] = (uint32_t)__popcll(gA.x)
                         | ((uint32_t)__popcll(gA.y) << 8)
                         | ((uint32_t)__popcll(gB.x) << 16)
                         | ((uint32_t)__popcll(gB.y) << 24);
    }

    int s100 = -1, s99 = -1;
    int cur = 0, nxt = 1, prv = 2;

    for (int it = 0; it < ITERS; ++it) {
        // ne for own (row, factor); row-local LDS, gated by row sync
        if (lane < NW) {
            const u64 X = s_inp[r][lane]
                ^ s_hist[r][cur][0][lane] ^ s_hist[r][cur][1][lane]
                ^ s_hist[r][cur][2][lane] ^ s_hist[r][cur][3][lane];
            s_ne[r][j][lane] = X ^ s_hist[r][cur][j][lane];
        }

        // ---- phase B: pc_v; lane = v; 8-deep hoisted b128 loads ----
        int pc = 0;
        #pragma unroll
        for (int hh = 0; hh < 2; ++hh) {
            ulonglong2 gB[8];
            #pragma unroll
            for (int k = 0; k < 8; ++k)
                gB[k] = tB[((hh << 3) | k) << 6];
            #pragma unroll
            for (int k = 0; k < 8; ++k) {
                const int w2 = (hh << 3) | k;
                const ulonglong2 nn =
                    *(const ulonglong2*)&s_ne[r][j][w2 << 1];
                pc += (int)__popcll(nn.x ^ gB[k].x)
                    + (int)__popcll(nn.y ^ gB[k].y);
            }
        }
        const int sp = wave_sum_dpp(pc);           // DPP sum, ~60cyc

        // ---- mean-centered exact decomposition, 7-bit clip ----
        const int mean = sp >> 6;
        const int dev  = pc - mean;
        const int devc = dev < -64 ? -64 : (dev > 63 ? 63 : dev);
        const int ex   = dev - devc;
        const int u    = devc + 64;       // 0..127, 7 planes
        const u64 c0 = __ballot(u & 1),  c1 = __ballot(u & 2);
        const u64 c2 = __ballot(u & 4),  c3 = __ballot(u & 8);
        const u64 c4 = __ballot(u & 16), c5 = __ballot(u & 32);
        const u64 c6 = __ballot(u & 64);
        u64 om = __ballot(ex != 0);
        const int nov = (int)__popcll(om);
        int ov0 = 0, ov1 = 0, oe0 = 0, oe1 = 0;
        if (nov > 0) {
            ov0 = __builtin_ctzll(om); om &= om - 1;
            oe0 = 4 * __builtin_amdgcn_readlane(ex, ov0);
            if (nov > 1) {
                ov1 = __builtin_ctzll(om); om &= om - 1;
                oe1 = 4 * __builtin_amdgcn_readlane(ex, ov1);
            }
        }
        const int base = 131072 - 2 * sp;
        const int cmul = 4 * mean - 4352;      // C=64 derivation

        // ---- phase C: lane = d%64; results collected, written once ----
        u64 nws[NW];
        if (__builtin_expect(nov <= 2, 1)) {      // hot: branch-free body
            #pragma unroll
            for (int hh = 0; hh < 2; ++hh) {
                ulonglong2 gT[8];
                #pragma unroll
                for (int k = 0; k < 8; ++k)
                    gT[k] = tT[((hh << 3) | k) << 6];
                #pragma unroll
                for (int k = 0; k < 8; ++k) {
                    const int w2 = (hh << 3) | k;
                    PCW_HOT(gT[k].x, (w2 << 1))
                    PCW_HOT(gT[k].y, (w2 << 1) + 1)
                }
            }
        } else {                                   // cold: exact fallback
            #pragma unroll
            for (int hh = 0; hh < 2; ++hh) {
                ulonglong2 gT[8];
                #pragma unroll
                for (int k = 0; k < 8; ++k)
                    gT[k] = tT[((hh << 3) | k) << 6];
                #pragma unroll
                for (int k = 0; k < 8; ++k) {
                    const int w2 = (hh << 3) | k;
                    PCW_COLD(gT[k].x, (w2 << 1))
                    PCW_COLD(gT[k].y, (w2 << 1) + 1)
                }
            }
        }
        // single exec-guarded write block: 16x ds_write_b128
        if (lane == 0) {
            #pragma unroll
            for (int w2 = 0; w2 < 16; ++w2) {
                ulonglong2 t2;
                t2.x = nws[w2 << 1];
                t2.y = nws[(w2 << 1) + 1];
                *(ulonglong2*)&s_hist[r][nxt][j][w2 << 1] = t2;
            }
        }

        // ---- period<=2 flags (parity slot) ----
        int d1 = 0, d2 = 0;
        if (lane < NW) {
            const u64 a = s_hist[r][nxt][j][lane];
            d1 = (a != s_hist[r][cur][j][lane]);
            d2 = (a != s_hist[r][prv][j][lane]);  // it=0 garbage, guarded
        }
        const u64 b1 = __ballot(d1), b2 = __ballot(d2);
        if (lane == 0)
            s_conv[it & 1][r][j] = (b1 == 0 ? 1 : 0) | (b2 == 0 ? 2 : 0);

        // ---- per-row semaphore sync ----
        __threadfence_block();                    // drain own LDS writes
        if (lane == 0) atomicAdd(&s_sem[r], 1);
        const int tgt = (it + 1) << 2;
        while (*vsem < tgt) __builtin_amdgcn_s_sleep(1);
        __threadfence_block();                    // no hoisting of reads

        // ---- per-row decision ----
        const int p = it & 1;
        const int flr = s_conv[p][r][0] & s_conv[p][r][1]
                      & s_conv[p][r][2] & s_conv[p][r][3];
        if ((flr & 1) || (it >= 1 && (flr & 2))) {
            if (flr & 1) { s100 = nxt; s99 = nxt; }
            else {
                s100 = (((ITERS - it) & 1) == 0) ? cur : nxt;
                s99  = (s100 == nxt) ? cur : nxt;
            }
            break;
        }
        const int t3 = prv; prv = cur; cur = nxt; nxt = t3;
    }
    if (s100 < 0) { s100 = cur; s99 = prv; }   // natural end, post-rotation

    // ---- epilogue, fully row-local ----
    int pcO = 0;
    #pragma unroll
    for (int w2 = 0; w2 < 16; ++w2) {
        const ulonglong2 g  = tB[w2 << 6];
        const ulonglong2 hh = *(const ulonglong2*)&s_hist[r][s100][j][w2 << 1];
        pcO += (int)__popcll(hh.x ^ g.x) + (int)__popcll(hh.y ^ g.y);
    }
    const int simF = ND - (pcO << 1);
    const int aF   = simF < 0 ? -simF : simF;
    int key = (aF << 6) | (63 - lane);
    #pragma unroll
    for (int off = 32; off > 0; off >>= 1) {
        const int t1 = __shfl_xor(key, off);
        key = key > t1 ? key : t1;
    }

    // max_sims[-1] = ND - 2*min_v pc on ne(est_99)
    int pc9 = 0;
    #pragma unroll
    for (int w2 = 0; w2 < 16; ++w2) {
        const ulonglong2 g = tB[w2 << 6];
        const int w = w2 << 1;
        const u64 X0 = s_inp[r][w]
            ^ s_hist[r][s99][0][w] ^ s_hist[r][s99][1][w]
            ^ s_hist[r][s99][2][w] ^ s_hist[r][s99][3][w];
        const u64 n0 = X0 ^ s_hist[r][s99][j][w];
        const u64 X1 = s_inp[r][w + 1]
            ^ s_hist[r][s99][0][w + 1] ^ s_hist[r][s99][1][w + 1]
            ^ s_hist[r][s99][2][w + 1] ^ s_hist[r][s99][3][w + 1];
        const u64 n1 = X1 ^ s_hist[r][s99][j][w + 1];
        pc9 += (int)__popcll(n0 ^ g.x) + (int)__popcll(n1 ^ g.y);
    }
    int mn9 = pc9;
    #pragma unroll
    for (int off = 32; off > 0; off >>= 1) {
        const int a1 = __shfl_xor(mn9, off);
        mn9 = mn9 < a1 ? mn9 : a1;
    }
    if (lane == 0) {
        out[OFF_OUT + (row << 2) + j] = (float)(63 - (key & 63));
        out[OFF_MS  + (row << 2) + j] = (float)(ND - 2 * mn9);
    }

    // unpack est_100: wave (r,j) writes its own factor's 2048 floats
    #pragma unroll 4
    for (int k = 0; k < NW; ++k) {
        const u64 wrd = s_hist[r][s100][j][k];
        out[(row << 13) + (j << 11) + (k << 6) + lane] =
            ((wrd >> lane) & 1) ? -1.0f : 1.0f;
    }
    if (b == 0 && tid == 0) out[OFF_CONV] = 99.0f;
}

extern "C" void kernel_launch(void* const* d_in, const int* in_sizes, int n_in,
                              void* d_out, int out_size, void* d_ws, size_t ws_size,
                              hipStream_t stream) {
    const float* inp  = (const float*)d_in[0];
    const float* est0 = (const float*)d_in[1];
    const float* cb   = (const float*)d_in[2];
    float* out = (float*)d_out;
    u64* cbB = (u64*)d_ws;                 // 8192 words
    u64* cbT = cbB + NF * 16 * 64 * 2;     // 8192 words (128 KB of ws total)

    pack_cb_kernel<<<64, 256, 0, stream>>>(cb, cbB, cbT);
    resonator_kernel<<<NB / NRB, 1024, 0, stream>>>(inp, est0, cbB, cbT, out);
}